// Round 10
// baseline (2088.258 us; speedup 1.0000x reference)
//
#include <hip/hip_runtime.h>
#include <math.h>

#define NN 50000
#define EE 800000
#define GG 256

typedef unsigned short u16;
typedef unsigned int u32;
typedef __attribute__((ext_vector_type(4))) float f32x4;
typedef __attribute__((ext_vector_type(8))) short bf16x8;

__device__ __forceinline__ float elu_f(float x) { return x > 0.f ? x : expm1f(x); }

__device__ __forceinline__ unsigned fenc(float f) {
  unsigned b = __float_as_uint(f);
  return (b & 0x80000000u) ? ~b : (b | 0x80000000u);
}
__device__ __forceinline__ float fdec(unsigned u) {
  return __uint_as_float((u & 0x80000000u) ? (u ^ 0x80000000u) : ~u);
}
__device__ __forceinline__ u16 f2b(float f) {
  u32 u = __float_as_uint(f);
  u32 r = (u + 0x7fffu + ((u >> 16) & 1u)) >> 16;
  return (u16)r;
}
__device__ __forceinline__ float bf2f(u16 u) { return __uint_as_float(((u32)u) << 16); }
__device__ __forceinline__ float lo2f(u32 p) { return __uint_as_float(p << 16); }
__device__ __forceinline__ float hi2f(u32 p) { return __uint_as_float(p & 0xffff0000u); }

__device__ __forceinline__ float wred64(float v) {
#pragma unroll
  for (int m = 32; m; m >>= 1) v += __shfl_xor(v, m, 64);
  return v;
}

// ---------------- generic tiled f32 GEMM: C = act(A@B + bias (+C)) ----------------
__global__ __launch_bounds__(256) void gemm_kernel(
    const float* __restrict__ A, const float* __restrict__ B,
    const float* __restrict__ bias, float* __restrict__ C,
    int M, int Nn, int K, int act, int accum) {
  __shared__ float As[16][68];
  __shared__ float Bs[16][68];
  const int bm = blockIdx.y * 64;
  const int bn = blockIdx.x * 64;
  const int tid = threadIdx.x;
  const int tx = tid & 15, ty = tid >> 4;
  const int lr = tid >> 2;
  const int lk = (tid & 3) << 2;
  float acc[4][4] = {};
  for (int k0 = 0; k0 < K; k0 += 16) {
    int arow = bm + lr;
    float4 a4 = {0.f, 0.f, 0.f, 0.f};
    if (arow < M) a4 = *reinterpret_cast<const float4*>(A + (size_t)arow * K + k0 + lk);
    As[lk + 0][lr] = a4.x; As[lk + 1][lr] = a4.y;
    As[lk + 2][lr] = a4.z; As[lk + 3][lr] = a4.w;
    float4 b4 = *reinterpret_cast<const float4*>(B + (size_t)(k0 + ty) * Nn + bn + tx * 4);
    *reinterpret_cast<float4*>(&Bs[ty][tx * 4]) = b4;
    __syncthreads();
#pragma unroll
    for (int kk = 0; kk < 16; ++kk) {
      float4 av = *reinterpret_cast<const float4*>(&As[kk][ty * 4]);
      float4 bv = *reinterpret_cast<const float4*>(&Bs[kk][tx * 4]);
      float a_[4] = {av.x, av.y, av.z, av.w};
      float b_[4] = {bv.x, bv.y, bv.z, bv.w};
#pragma unroll
      for (int ii = 0; ii < 4; ++ii)
#pragma unroll
        for (int jj = 0; jj < 4; ++jj)
          acc[ii][jj] = fmaf(a_[ii], b_[jj], acc[ii][jj]);
    }
    __syncthreads();
  }
#pragma unroll
  for (int ii = 0; ii < 4; ++ii) {
    int row = bm + ty * 4 + ii;
    if (row >= M) continue;
#pragma unroll
    for (int jj = 0; jj < 4; ++jj) {
      int col = bn + tx * 4 + jj;
      float val = acc[ii][jj];
      if (bias) val += bias[col];
      if (accum) val += C[(size_t)row * Nn + col];
      if (act) val = elu_f(val);
      C[(size_t)row * Nn + col] = val;
    }
  }
}

// ---------------- CSR build ----------------
__global__ void csr_hist(const int* __restrict__ dst, int* __restrict__ deg) {
  int e = blockIdx.x * blockDim.x + threadIdx.x;
  if (e < EE) atomicAdd(&deg[dst[e]], 1);
}

__global__ void scan1(const int* __restrict__ deg, int* __restrict__ pre,
                      int* __restrict__ bsum, int n) {
  __shared__ int s[256];
  int t = threadIdx.x;
  int i = blockIdx.x * 256 + t;
  int v = (i < n) ? deg[i] : 0;
  s[t] = v;
  __syncthreads();
  for (int off = 1; off < 256; off <<= 1) {
    int tmp = (t >= off) ? s[t - off] : 0;
    __syncthreads();
    s[t] += tmp;
    __syncthreads();
  }
  if (i < n) pre[i] = s[t] - v;
  if (t == 255) bsum[blockIdx.x] = s[255];
}

__global__ void scan2(int* __restrict__ bsum, int nb) {
  __shared__ int s[256];
  int t = threadIdx.x;
  int v = (t < nb) ? bsum[t] : 0;
  s[t] = v;
  __syncthreads();
  for (int off = 1; off < 256; off <<= 1) {
    int tmp = (t >= off) ? s[t - off] : 0;
    __syncthreads();
    s[t] += tmp;
    __syncthreads();
  }
  if (t < nb) bsum[t] = s[t] - v;
}

__global__ void scan3(const int* __restrict__ pre, const int* __restrict__ bsum,
                      const int* __restrict__ deg, int* __restrict__ row_start,
                      int* __restrict__ cursor, int n) {
  int i = blockIdx.x * 256 + threadIdx.x;
  if (i < n) {
    int v = pre[i] + bsum[blockIdx.x];
    row_start[i] = v;
    cursor[i] = v;
    if (i == n - 1) row_start[n] = v + deg[i];
  }
}

__global__ void gstart_build(const int* __restrict__ batch, int* __restrict__ gstart) {
  int n = blockIdx.x * blockDim.x + threadIdx.x;
  if (n > NN) return;
  int b = (n < NN) ? batch[n] : GG;
  int pb = (n == 0) ? -1 : batch[n - 1];
  for (int g = pb + 1; g <= b; ++g) gstart[g] = n;
}

__global__ void csr_pos(const int* __restrict__ src, const int* __restrict__ dst,
                        int* __restrict__ cursor, int* __restrict__ csr_src,
                        int* __restrict__ epos) {
  int e = blockIdx.x * blockDim.x + threadIdx.x;
  if (e >= EE) return;
  int pos = atomicAdd(&cursor[dst[e]], 1);
  csr_src[pos] = src[e];
  epos[e] = pos;
}

__global__ void out_hist(const int* __restrict__ csr_src, int* __restrict__ odeg) {
  int pos = blockIdx.x * blockDim.x + threadIdx.x;
  if (pos < EE) atomicAdd(&odeg[csr_src[pos]], 1);
}

__global__ void out_fill(const int* __restrict__ csr_src, int* __restrict__ ocursor,
                         int* __restrict__ operm) {
  int pos = blockIdx.x * blockDim.x + threadIdx.x;
  if (pos < EE) {
    int slot = atomicAdd(&ocursor[csr_src[pos]], 1);
    operm[slot] = pos;
  }
}

__global__ void sgstart_build(const int* __restrict__ out_start, const int* __restrict__ gstart,
                              int* __restrict__ sg_start) {
  int t = blockIdx.x * blockDim.x + threadIdx.x;
  if (t <= GG) sg_start[t] = out_start[gstart[t]];
}

// we0[16x64] -> split bf16 fragments, K padded to 32 (k>=16 -> 0)
__global__ void build_we0frag(const float* __restrict__ we0, u16* __restrict__ wf_hi,
                              u16* __restrict__ wf_lo) {
  int idx = blockIdx.x * 256 + threadIdx.x;  // 2048
  if (idx >= 2048) return;
  int j = idx & 7, lane = (idx >> 3) & 63, t = idx >> 9;
  int k = (lane >> 4) * 8 + j;
  int c = t * 16 + (lane & 15);
  float w = (k < 16) ? we0[(size_t)k * 64 + c] : 0.f;
  u16 hi = f2b(w);
  wf_hi[idx] = hi;
  wf_lo[idx] = f2b(w - bf2f(hi));
}

// MFMA edge encoder: ea[epos[e]] = elu(edge_attr[e] @ we0 + be0), 16 edges/wave
__global__ __launch_bounds__(256) void ea_enc_mfma(const float* __restrict__ edge_attr,
                                                   const u16* __restrict__ wf_hi,
                                                   const u16* __restrict__ wf_lo,
                                                   const float* __restrict__ be0,
                                                   const int* __restrict__ epos,
                                                   u16* __restrict__ ea) {
  int lane = threadIdx.x & 63;
  int gwave = (blockIdx.x * 256 + threadIdx.x) >> 6;
  int nwaves = (gridDim.x * 256) >> 6;
  bf16x8 bh[4], bl[4];
#pragma unroll
  for (int t = 0; t < 4; ++t) {
    bh[t] = *reinterpret_cast<const bf16x8*>(wf_hi + ((size_t)(t * 64 + lane)) * 8);
    bl[t] = *reinterpret_cast<const bf16x8*>(wf_lo + ((size_t)(t * 64 + lane)) * 8);
  }
  float bias_c[4];
#pragma unroll
  for (int t = 0; t < 4; ++t) bias_c[t] = be0[t * 16 + (lane & 15)];
  const int rif = lane & 15;
  const int kg = lane >> 4;
  for (int mt = gwave; mt < EE / 16; mt += nwaves) {
    int base = mt * 16;
    bf16x8 ah = {}, al = {};
    if (kg < 2) {
      const float* ap = edge_attr + (size_t)(base + rif) * 16 + kg * 8;
      float4 f0 = *reinterpret_cast<const float4*>(ap);
      float4 f1 = *reinterpret_cast<const float4*>(ap + 4);
      float fv[8] = {f0.x, f0.y, f0.z, f0.w, f1.x, f1.y, f1.z, f1.w};
#pragma unroll
      for (int jj = 0; jj < 8; ++jj) {
        u16 hi = f2b(fv[jj]);
        ah[jj] = (short)hi;
        al[jj] = (short)f2b(fv[jj] - bf2f(hi));
      }
    }
    f32x4 acc[4] = {};
#pragma unroll
    for (int t = 0; t < 4; ++t) {
      acc[t] = __builtin_amdgcn_mfma_f32_16x16x32_bf16(ah, bh[t], acc[t], 0, 0, 0);
      acc[t] = __builtin_amdgcn_mfma_f32_16x16x32_bf16(ah, bl[t], acc[t], 0, 0, 0);
      acc[t] = __builtin_amdgcn_mfma_f32_16x16x32_bf16(al, bh[t], acc[t], 0, 0, 0);
    }
#pragma unroll
    for (int rg = 0; rg < 4; ++rg) {
      int pr = epos[base + kg * 4 + rg];
#pragma unroll
      for (int t = 0; t < 4; ++t)
        ea[(size_t)pr * 64 + t * 16 + rif] = f2b(elu_f(acc[t][rg] + bias_c[t]));
    }
  }
}

// ---------------- graph LayerNorm ----------------
__global__ __launch_bounds__(256) void ln_stats_block(const float* __restrict__ h,
                                                      const int* __restrict__ gstart,
                                                      float* __restrict__ gmean,
                                                      float* __restrict__ grstd) {
  __shared__ float ls[4], lss[4];
  int g = blockIdx.x, t = threadIdx.x;
  int n0 = gstart[g], n1 = gstart[g + 1];
  int total4 = (n1 - n0) * 32;
  const float4* base = (const float4*)(h + (size_t)n0 * 128);
  float s = 0.f, ss = 0.f;
  for (int i = t; i < total4; i += 256) {
    float4 v = base[i];
    s += v.x + v.y + v.z + v.w;
    ss += v.x * v.x + v.y * v.y + v.z * v.z + v.w * v.w;
  }
  s = wred64(s);
  ss = wred64(ss);
  if ((t & 63) == 0) { ls[t >> 6] = s; lss[t >> 6] = ss; }
  __syncthreads();
  if (t == 0) {
    float S = ls[0] + ls[1] + ls[2] + ls[3];
    float SS = lss[0] + lss[1] + lss[2] + lss[3];
    float cnt = fmaxf((float)(n1 - n0) * 128.f, 1.0f);
    float mean = S / cnt;
    float var = fmaxf(SS / cnt - mean * mean, 0.f);
    gmean[g] = mean;
    grstd[g] = rsqrtf(var + 1e-5f);
  }
}

// LN final from fused gstat (counts from gstart)
__global__ void ln_final2(const float* __restrict__ gstat, const int* __restrict__ gstart,
                          float* __restrict__ gmean, float* __restrict__ grstd) {
  int t = threadIdx.x;
  if (t < GG) {
    float cnt = fmaxf((float)(gstart[t + 1] - gstart[t]) * 128.f, 1.0f);
    float mean = gstat[t] / cnt;
    float var = fmaxf(gstat[GG + t] / cnt - mean * mean, 0.f);
    gmean[t] = mean;
    grstd[t] = rsqrtf(var + 1e-5f);
  }
}

// LN apply -> split bf16 (hi + lo residual)
__global__ __launch_bounds__(256) void ln_apply(const float* __restrict__ in,
                                                u16* __restrict__ out_hi,
                                                u16* __restrict__ out_lo,
                                                const int* __restrict__ batch,
                                                const float* __restrict__ gmean,
                                                const float* __restrict__ grstd,
                                                const float* __restrict__ gamma,
                                                const float* __restrict__ beta) {
  int idx = blockIdx.x * blockDim.x + threadIdx.x;
  if (idx >= NN * 32) return;
  int n = idx >> 5, c4 = (idx & 31) * 4;
  int g = batch[n];
  float mean = gmean[g], rstd = grstd[g];
  float4 xv = *reinterpret_cast<const float4*>(in + (size_t)n * 128 + c4);
  float4 gv = *reinterpret_cast<const float4*>(gamma + c4);
  float4 bv = *reinterpret_cast<const float4*>(beta + c4);
  float v0 = elu_f((xv.x - mean) * rstd * gv.x + bv.x);
  float v1 = elu_f((xv.y - mean) * rstd * gv.y + bv.y);
  float v2 = elu_f((xv.z - mean) * rstd * gv.z + bv.z);
  float v3 = elu_f((xv.w - mean) * rstd * gv.w + bv.w);
  u16 h0 = f2b(v0), h1 = f2b(v1), h2 = f2b(v2), h3 = f2b(v3);
  uint2 hi = {(u32)h0 | ((u32)h1 << 16), (u32)h2 | ((u32)h3 << 16)};
  uint2 lo = {(u32)f2b(v0 - bf2f(h0)) | ((u32)f2b(v1 - bf2f(h1)) << 16),
              (u32)f2b(v2 - bf2f(h2)) | ((u32)f2b(v3 - bf2f(h3)) << 16)};
  *reinterpret_cast<uint2*>(out_hi + (size_t)n * 128 + c4) = hi;
  *reinterpret_cast<uint2*>(out_lo + (size_t)n * 128 + c4) = lo;
}

// ---------------- per-layer weight transforms ----------------
__global__ void build_wqe(const float* __restrict__ wq, const float* __restrict__ bq,
                          const float* __restrict__ we, float* __restrict__ WQE,
                          float* __restrict__ bqe) {
  int col = threadIdx.x;
  int row = blockIdx.x;
  int hh = col >> 6, j = col & 63;
  const float* wrow = (row < 128) ? (wq + (size_t)row * 128) : bq;
  float acc = 0.f;
  for (int c = 0; c < 64; ++c) acc += wrow[hh * 64 + c] * we[(size_t)j * 128 + hh * 64 + c];
  if (row < 128) WQE[(size_t)row * 128 + col] = acc;
  else bqe[col] = acc;
}

// fused: Wfrag (hi/lo) + wef (hi/lo) + ball + gstat zeroing
__global__ void build_wfrag2(const float* __restrict__ wq, const float* __restrict__ wk,
                             const float* __restrict__ wv, const float* __restrict__ WQE,
                             const float* __restrict__ wsk, const float* __restrict__ we,
                             const float* __restrict__ bq, const float* __restrict__ bk,
                             const float* __restrict__ bv, const float* __restrict__ bqe,
                             const float* __restrict__ bsk,
                             u16* __restrict__ Wfrag_hi, u16* __restrict__ Wfrag_lo,
                             u16* __restrict__ wef_hi, u16* __restrict__ wef_lo,
                             float* __restrict__ ball, float* __restrict__ gstat) {
  int idx = blockIdx.x * 256 + threadIdx.x;
  if (idx < 81920) {
    int j = idx & 7, lane = (idx >> 3) & 63, rest = idx >> 9;
    int tg = rest % 40, s = rest / 40;
    int k = s * 32 + (lane >> 4) * 8 + j;
    int col = tg * 16 + (lane & 15);
    int sel = col >> 7, c = col & 127;
    const float* src = sel == 0 ? wq : sel == 1 ? wk : sel == 2 ? wv : sel == 3 ? WQE : wsk;
    float w = src[(size_t)k * 128 + c];
    u16 hi = f2b(w);
    Wfrag_hi[idx] = hi;
    Wfrag_lo[idx] = f2b(w - bf2f(hi));
  } else if (idx < 90112) {
    int i2 = idx - 81920;
    int j = i2 & 7, lane = (i2 >> 3) & 63, rest = i2 >> 9;
    int t = rest & 3, hh = (rest >> 2) & 1, s = rest >> 3;
    int k = s * 32 + (lane >> 4) * 8 + j;
    int col = hh * 64 + t * 16 + (lane & 15);
    float w = we[(size_t)k * 128 + col];
    u16 hi = f2b(w);
    wef_hi[i2] = hi;
    wef_lo[i2] = f2b(w - bf2f(hi));
  } else if (idx < 90112 + 2 * GG) {
    gstat[idx - 90112] = 0.f;
  }
  if (idx < 640) {
    int sel = idx >> 7, c = idx & 127;
    const float* s2 = sel == 0 ? bq : sel == 1 ? bk : sel == 2 ? bv : sel == 3 ? bqe : bsk;
    ball[idx] = s2[c];
  }
}

// up[64x64] f32 -> bf16 fragments
__global__ void build_upfrag(const float* __restrict__ up, u16* __restrict__ upfrag) {
  int idx = blockIdx.x * 256 + threadIdx.x;
  if (idx >= 4096) return;
  int j = idx & 7, lane = (idx >> 3) & 63, st = idx >> 9;
  int s = st >> 2, t = st & 3;
  int k = s * 32 + (lane >> 4) * 8 + j;
  int c = t * 16 + (lane & 15);
  upfrag[idx] = f2b(up[k * 64 + c]);
}

// W2 = up @ re_w; bvec = ub @ re_w; also zero gsum_in (GG*64). Launch 64 blocks.
__global__ void build_w2(const float* __restrict__ up, const float* __restrict__ ub,
                         const float* __restrict__ re_w, float* __restrict__ W2,
                         float* __restrict__ bvec, float* __restrict__ gsum_in) {
  int idx = blockIdx.x * 256 + threadIdx.x;
  if (idx < 64 * 128) {
    int k_ = idx >> 7, c = idx & 127;
    float a = 0.f;
    for (int j = 0; j < 64; ++j) a = fmaf(up[k_ * 64 + j], re_w[j * 128 + c], a);
    W2[idx] = a;
  } else if (idx < 64 * 128 + 128) {
    int c = idx - 64 * 128;
    float a = 0.f;
    for (int j = 0; j < 64; ++j) a = fmaf(ub[j], re_w[j * 128 + c], a);
    bvec[c] = a;
  }
  if (idx < GG * 64) gsum_in[idx] = 0.f;
}

// ---------------- split-precision MFMA node GEMM ----------------
// nodebuf row layout (u16 idx): q[0..127] | qe[128..255] | kv interleaved [256..511]
__global__ __launch_bounds__(256) void node_gemm(const u16* __restrict__ h_hi,
                                                 const u16* __restrict__ h_lo,
                                                 const u16* __restrict__ Wfrag_hi,
                                                 const u16* __restrict__ Wfrag_lo,
                                                 const float* __restrict__ ball,
                                                 u16* __restrict__ nodebuf,
                                                 float* __restrict__ hn) {
  int tid = threadIdx.x;
  int lane = tid & 63;
  int wv = tid >> 6;
  int cb = blockIdx.x;
  int rbase = blockIdx.y * 64 + wv * 16;
  int rif = lane & 15, kg = lane >> 4;
  f32x4 acc[4] = {};
  int arow = rbase + rif;
  bool rowok = arow < NN;
  const u16* aph = h_hi + (size_t)arow * 128 + kg * 8;
  const u16* apl = h_lo + (size_t)arow * 128 + kg * 8;
#pragma unroll
  for (int s = 0; s < 4; ++s) {
    bf16x8 ah = {}, al = {};
    if (rowok) {
      ah = *reinterpret_cast<const bf16x8*>(aph + s * 32);
      al = *reinterpret_cast<const bf16x8*>(apl + s * 32);
    }
#pragma unroll
    for (int t = 0; t < 4; ++t) {
      size_t fo = ((size_t)((s * 40 + cb * 4 + t) * 64 + lane)) * 8;
      bf16x8 bh = *reinterpret_cast<const bf16x8*>(Wfrag_hi + fo);
      bf16x8 bl = *reinterpret_cast<const bf16x8*>(Wfrag_lo + fo);
      acc[t] = __builtin_amdgcn_mfma_f32_16x16x32_bf16(ah, bh, acc[t], 0, 0, 0);
      acc[t] = __builtin_amdgcn_mfma_f32_16x16x32_bf16(ah, bl, acc[t], 0, 0, 0);
      acc[t] = __builtin_amdgcn_mfma_f32_16x16x32_bf16(al, bh, acc[t], 0, 0, 0);
    }
  }
#pragma unroll
  for (int t = 0; t < 4; ++t) {
    int col = (cb * 4 + t) * 16 + rif;
    float bia = ball[col];
#pragma unroll
    for (int rg = 0; rg < 4; ++rg) {
      int row = rbase + kg * 4 + rg;
      if (row < NN) {
        float val = acc[t][rg] + bia;
        if (col < 512) {
          int idx;
          if (col < 128) idx = col;
          else if (col < 256) { int c1 = col - 128; idx = 256 + ((c1 >> 1) << 2) + (c1 & 1); }
          else if (col < 384) { int c2 = col - 256; idx = 256 + ((c2 >> 1) << 2) + 2 + (c2 & 1); }
          else idx = 128 + (col - 384);
          nodebuf[(size_t)row * 512 + idx] = f2b(val);
        } else {
          hn[(size_t)row * 128 + col - 512] = val;
        }
      }
    }
  }
}

// ---------------- MFMA edge GEMM: ea = elu(ea @ up + ub), in place ----------------
__global__ __launch_bounds__(256) void edge_gemm(u16* __restrict__ ea,
                                                 const u16* __restrict__ upfrag,
                                                 const float* __restrict__ ub) {
  int lane = threadIdx.x & 63;
  int gwave = (blockIdx.x * 256 + threadIdx.x) >> 6;
  int nwaves = (gridDim.x * 256) >> 6;
  bf16x8 bfrag[2][4];
#pragma unroll
  for (int s = 0; s < 2; ++s)
#pragma unroll
    for (int t = 0; t < 4; ++t)
      bfrag[s][t] = *reinterpret_cast<const bf16x8*>(upfrag + ((size_t)((s * 4 + t) * 64 + lane)) * 8);
  float bias_c[4];
#pragma unroll
  for (int t = 0; t < 4; ++t) bias_c[t] = ub[t * 16 + (lane & 15)];
  const int rif = lane & 15;
  const int kg = lane >> 4;
  for (int mt = gwave; mt < EE / 16; mt += nwaves) {
    size_t rowbase = (size_t)mt * 16;
    const u16* arow = ea + (rowbase + rif) * 64;
    bf16x8 a0 = *reinterpret_cast<const bf16x8*>(arow + kg * 8);
    bf16x8 a1 = *reinterpret_cast<const bf16x8*>(arow + 32 + kg * 8);
    f32x4 acc[4] = {};
#pragma unroll
    for (int t = 0; t < 4; ++t) {
      acc[t] = __builtin_amdgcn_mfma_f32_16x16x32_bf16(a0, bfrag[0][t], acc[t], 0, 0, 0);
      acc[t] = __builtin_amdgcn_mfma_f32_16x16x32_bf16(a1, bfrag[1][t], acc[t], 0, 0, 0);
    }
#pragma unroll
    for (int t = 0; t < 4; ++t)
#pragma unroll
      for (int rg = 0; rg < 4; ++rg) {
        float val = acc[t][rg] + bias_c[t];
        ea[(rowbase + kg * 4 + rg) * 64 + t * 16 + rif] = f2b(elu_f(val));
      }
  }
}

// ---------------- split-precision MFMA BD GEMM + fused LN stats ----------------
__global__ __launch_bounds__(256) void bd_gemm(const u16* __restrict__ r_hi,
                                               const u16* __restrict__ r_lo,
                                               const u16* __restrict__ wef_hi,
                                               const u16* __restrict__ wef_lo,
                                               float* __restrict__ hn,
                                               const int* __restrict__ batch,
                                               float* __restrict__ gstat) {
  int tid = threadIdx.x;
  int lane = tid & 63;
  int w = blockIdx.x * 4 + (tid >> 6);
  if (w >= NN / 16) return;
  int rif = lane & 15, kg = lane >> 4;
  size_t rowbase = (size_t)w * 16;
  const u16* ahb = r_hi + (rowbase + rif) * 128;
  const u16* alb = r_lo + (rowbase + rif) * 128;
  f32x4 acc[2][4] = {};
#pragma unroll
  for (int hh = 0; hh < 2; ++hh)
#pragma unroll
    for (int s = 0; s < 2; ++s) {
      int ko = hh * 64 + s * 32 + kg * 8;
      bf16x8 ah = *reinterpret_cast<const bf16x8*>(ahb + ko);
      bf16x8 al = *reinterpret_cast<const bf16x8*>(alb + ko);
#pragma unroll
      for (int t = 0; t < 4; ++t) {
        size_t fo = ((size_t)((((s * 2 + hh) * 4 + t)) * 64 + lane)) * 8;
        bf16x8 bh = *reinterpret_cast<const bf16x8*>(wef_hi + fo);
        bf16x8 bl = *reinterpret_cast<const bf16x8*>(wef_lo + fo);
        acc[hh][t] = __builtin_amdgcn_mfma_f32_16x16x32_bf16(ah, bh, acc[hh][t], 0, 0, 0);
        acc[hh][t] = __builtin_amdgcn_mfma_f32_16x16x32_bf16(ah, bl, acc[hh][t], 0, 0, 0);
        acc[hh][t] = __builtin_amdgcn_mfma_f32_16x16x32_bf16(al, bh, acc[hh][t], 0, 0, 0);
      }
    }
#pragma unroll
  for (int rg = 0; rg < 4; ++rg) {
    size_t row = rowbase + kg * 4 + rg;
    float s = 0.f, sq = 0.f;
#pragma unroll
    for (int hh = 0; hh < 2; ++hh)
#pragma unroll
      for (int t = 0; t < 4; ++t) {
        size_t off = row * 128 + hh * 64 + t * 16 + rif;
        float val = hn[off] + acc[hh][t][rg];
        hn[off] = val;
        s += val;
        sq += val * val;
      }
#pragma unroll
    for (int mm = 1; mm <= 8; mm <<= 1) {
      s += __shfl_xor(s, mm, 64);
      sq += __shfl_xor(sq, mm, 64);
    }
    if (rif == 0) {
      int g = batch[row];
      atomicAdd(&gstat[g], s);
      atomicAdd(&gstat[GG + g], sq);
    }
  }
}

// per-src-graph sum of current ea rows, chunked + atomic merge
__global__ __launch_bounds__(256) void gsum_pre(const u16* __restrict__ ea,
                                                const int* __restrict__ sg_start,
                                                const int* __restrict__ sg_perm,
                                                float* __restrict__ gsum_in) {
  __shared__ float red[8][64];
  int g = blockIdx.x, t = threadIdx.x;
  int c2 = t & 31;
  int rgrp = t >> 5;
  int gr = blockIdx.y * 8 + rgrp;
  int p0 = sg_start[g], p1 = sg_start[g + 1];
  float slo = 0.f, shi = 0.f;
  for (int i = p0 + gr; i < p1; i += 128) {
    int pos = sg_perm[i];
    u32 w = ((const u32*)ea)[(size_t)pos * 32 + c2];
    slo += lo2f(w);
    shi += hi2f(w);
  }
  red[rgrp][c2 * 2] = slo;
  red[rgrp][c2 * 2 + 1] = shi;
  __syncthreads();
  if (t < 64) {
    float a = 0.f;
#pragma unroll
    for (int rr = 0; rr < 8; ++rr) a += red[rr][t];
    atomicAdd(&gsum_in[(size_t)g * 64 + t], a);
  }
}

// embE = elu(gsum_in @ W2 + cnt*bvec + re_b)
__global__ void emb_e_kernel(const float* __restrict__ gsum_in, const int* __restrict__ sg_start,
                             const float* __restrict__ W2, const float* __restrict__ bvec,
                             const float* __restrict__ re_b, float* __restrict__ embE) {
  int g = blockIdx.x, c = threadIdx.x;
  float cnt = (float)(sg_start[g + 1] - sg_start[g]);
  float a = re_b[c] + cnt * bvec[c];
  for (int k_ = 0; k_ < 64; ++k_) a = fmaf(gsum_in[(size_t)g * 64 + k_], W2[k_ * 128 + c], a);
  embE[(size_t)g * 128 + c] = elu_f(a);
}

// ---------------- fused flash attention: one wave per dst, 2 edges/wave ----------------
// lanes 0-31: edge A, lanes 32-63: edge B; each lane owns 4 channels.
__global__ __launch_bounds__(256) void attn_node(const u32* __restrict__ nb32,
                                                 const u32* __restrict__ ea32,
                                                 const int* __restrict__ row_start,
                                                 const int* __restrict__ csr_src,
                                                 float* __restrict__ hn,
                                                 u32* __restrict__ r_hi,
                                                 u32* __restrict__ r_lo) {
  int d = (blockIdx.x * blockDim.x + threadIdx.x) >> 6;
  if (d >= NN) return;
  int lane = threadIdx.x & 63;
  int half = lane >> 5;
  int l = lane & 31;
  int li = l & 15;
  int qi = (l >> 4) * 32 + li * 2;  // u32 channel-pair index (0..63)
  int p0 = row_start[d], p1 = row_start[d + 1];
  if (p0 == p1) {
    if (!half) {
      uint2 z = {0u, 0u};
      *reinterpret_cast<uint2*>(r_hi + (size_t)d * 64 + qi) = z;
      *reinterpret_cast<uint2*>(r_lo + (size_t)d * 64 + qi) = z;
    }
    return;
  }
  size_t dbase = (size_t)d * 256;
  uint2 qp = *reinterpret_cast<const uint2*>(nb32 + dbase + qi);
  uint2 qep = *reinterpret_cast<const uint2*>(nb32 + dbase + 64 + qi);
  float q0 = lo2f(qp.x), q1 = hi2f(qp.x), q2 = lo2f(qp.y), q3 = hi2f(qp.y);
  float g0 = lo2f(qep.x), g1 = hi2f(qep.x), g2 = lo2f(qep.y), g3 = hi2f(qep.y);
  int cnt = p1 - p0;
  int nIter = (cnt + 1) >> 1;
  float m = -3.4e38f, ss = 0.f;
  float a0 = 0.f, a1 = 0.f, a2 = 0.f, a3 = 0.f;
  float r0 = 0.f, r1 = 0.f, r2 = 0.f, r3 = 0.f;
  int i = half;
  bool vld = i < cnt;
  int pc = vld ? p0 + i : p0;
  int sc = csr_src[pc];
  uint4 kv = *reinterpret_cast<const uint4*>(nb32 + (size_t)sc * 256 + 128 + qi * 2);
  uint2 ev = *reinterpret_cast<const uint2*>(ea32 + (size_t)pc * 32 + li * 2);
  for (int j = 0; j < nIter; ++j) {
    int i2 = i + 2;
    bool nvld = i2 < cnt;
    int pn = nvld ? p0 + i2 : p0;
    int sn = csr_src[pn];
    uint4 kvn = *reinterpret_cast<const uint4*>(nb32 + (size_t)sn * 256 + 128 + qi * 2);
    uint2 evn = *reinterpret_cast<const uint2*>(ea32 + (size_t)pn * 32 + li * 2);
    float x0 = lo2f(ev.x), x1 = hi2f(ev.x), x2 = lo2f(ev.y), x3 = hi2f(ev.y);
    float p = q0 * lo2f(kv.x) + q1 * hi2f(kv.x) + q2 * lo2f(kv.z) + q3 * hi2f(kv.z) +
              g0 * x0 + g1 * x1 + g2 * x2 + g3 * x3;
#pragma unroll
    for (int mm = 1; mm <= 8; mm <<= 1) p += __shfl_xor(p, mm, 64);  // per-16-lane head sum
    float lg = vld ? p * 0.125f : -3.4e38f;
    float mn = fmaxf(m, lg);
    float f = __expf(m - mn), w = __expf(lg - mn);
    ss = ss * f + w;
    a0 = a0 * f + w * lo2f(kv.y); a1 = a1 * f + w * hi2f(kv.y);
    a2 = a2 * f + w * lo2f(kv.w); a3 = a3 * f + w * hi2f(kv.w);
    r0 = r0 * f + w * x0; r1 = r1 * f + w * x1;
    r2 = r2 * f + w * x2; r3 = r3 * f + w * x3;
    m = mn;
    i = i2; vld = nvld; kv = kvn; ev = evn;
  }
  // merge edge-halves
  float mo = __shfl_xor(m, 32, 64);
  float so = __shfl_xor(ss, 32, 64);
  float b0 = __shfl_xor(a0, 32, 64), b1 = __shfl_xor(a1, 32, 64);
  float b2 = __shfl_xor(a2, 32, 64), b3 = __shfl_xor(a3, 32, 64);
  float t0 = __shfl_xor(r0, 32, 64), t1 = __shfl_xor(r1, 32, 64);
  float t2 = __shfl_xor(r2, 32, 64), t3 = __shfl_xor(r3, 32, 64);
  float mn = fmaxf(m, mo);
  float fs = __expf(m - mn), fo = __expf(mo - mn);
  ss = ss * fs + so * fo;
  a0 = a0 * fs + b0 * fo; a1 = a1 * fs + b1 * fo;
  a2 = a2 * fs + b2 * fo; a3 = a3 * fs + b3 * fo;
  r0 = r0 * fs + t0 * fo; r1 = r1 * fs + t1 * fo;
  r2 = r2 * fs + t2 * fo; r3 = r3 * fs + t3 * fo;
  if (!half) {
    float inv = 1.f / ss;
    int ch0 = (l >> 4) * 64 + li * 4;
    float* hp = hn + (size_t)d * 128 + ch0;
    float4 hv = *reinterpret_cast<float4*>(hp);
    hv.x += a0 * inv; hv.y += a1 * inv; hv.z += a2 * inv; hv.w += a3 * inv;
    *reinterpret_cast<float4*>(hp) = hv;
    float rv0 = r0 * inv, rv1 = r1 * inv, rv2 = r2 * inv, rv3 = r3 * inv;
    u16 h0 = f2b(rv0), h1 = f2b(rv1), h2 = f2b(rv2), h3 = f2b(rv3);
    uint2 rh = {(u32)h0 | ((u32)h1 << 16), (u32)h2 | ((u32)h3 << 16)};
    uint2 rl = {(u32)f2b(rv0 - bf2f(h0)) | ((u32)f2b(rv1 - bf2f(h1)) << 16),
                (u32)f2b(rv2 - bf2f(h2)) | ((u32)f2b(rv3 - bf2f(h3)) << 16)};
    *reinterpret_cast<uint2*>(r_hi + (size_t)d * 64 + qi) = rh;
    *reinterpret_cast<uint2*>(r_lo + (size_t)d * 64 + qi) = rl;
  }
}

// ---------------- SAG pooling ----------------
__global__ __launch_bounds__(256) void node_dots(const float* __restrict__ hn,
                                                 const float* __restrict__ wrel,
                                                 const float* __restrict__ wroot,
                                                 float* __restrict__ hrel,
                                                 float* __restrict__ troot,
                                                 unsigned* __restrict__ gm,
                                                 float* __restrict__ gs) {
  int tid0 = blockIdx.x * blockDim.x + threadIdx.x;
  if (tid0 < GG) gm[tid0] = 0u;
  else if (tid0 < 2 * GG) gs[tid0 - GG] = 0.f;
  int n = tid0 >> 6;
  if (n >= NN) return;
  int lane = threadIdx.x & 63;
  float x0 = hn[(size_t)n * 128 + lane], x1 = hn[(size_t)n * 128 + 64 + lane];
  float tr = wred64(x0 * wrel[lane] + x1 * wrel[64 + lane]);
  float tt = wred64(x0 * wroot[lane] + x1 * wroot[64 + lane]);
  if (lane == 0) { hrel[n] = tr; troot[n] = tt; }
}

__global__ __launch_bounds__(256) void sag_gather(const float* __restrict__ hrel,
                                                  const float* __restrict__ troot,
                                                  const float* __restrict__ brel,
                                                  const int* __restrict__ row_start,
                                                  const int* __restrict__ csr_src,
                                                  const int* __restrict__ batch,
                                                  float* __restrict__ sc, unsigned* __restrict__ gm) {
  int n = blockIdx.x * blockDim.x + threadIdx.x;
  if (n >= NN) return;
  float s = 0.f;
  int p1 = row_start[n + 1];
  for (int pos = row_start[n]; pos < p1; ++pos) s += hrel[csr_src[pos]];
  float v = s + troot[n] + brel[0];
  sc[n] = v;
  atomicMax(&gm[batch[n]], fenc(v));
}

__global__ __launch_bounds__(256) void sag_exp(const float* __restrict__ sc,
                                               const int* __restrict__ batch,
                                               const unsigned* __restrict__ gm,
                                               float* __restrict__ gs, float* __restrict__ scp) {
  int n = blockIdx.x * blockDim.x + threadIdx.x;
  if (n >= NN) return;
  int g = batch[n];
  float p = __expf(sc[n] - fdec(gm[g]));
  scp[n] = p;
  atomicAdd(&gs[g], p);
}

__global__ void emb_block(const float* __restrict__ hn, const float* __restrict__ scp,
                          const float* __restrict__ gs, const int* __restrict__ gstart,
                          const float* __restrict__ embE, float* __restrict__ dstv) {
  __shared__ float part[2];
  int g = blockIdx.x, c = threadIdx.x;
  int n0 = gstart[g], n1 = gstart[g + 1];
  float invg = 1.f / gs[g];
  float acc = 0.f;
  for (int n = n0; n < n1; ++n) acc = fmaf(hn[(size_t)n * 128 + c], scp[n] * invg, acc);
  float val = acc * embE[(size_t)g * 128 + c];
  float sq = val * val;
#pragma unroll
  for (int mm = 32; mm; mm >>= 1) sq += __shfl_xor(sq, mm, 64);
  if ((c & 63) == 0) part[c >> 6] = sq;
  __syncthreads();
  float nrm = sqrtf(part[0] + part[1]);
  dstv[(size_t)g * 128 + c] = elu_f(val / fmaxf(nrm, 1e-12f));
}

__global__ void final_combine(const float* __restrict__ e0, const float* __restrict__ e1,
                              float* __restrict__ out) {
  int idx = blockIdx.x * blockDim.x + threadIdx.x;
  if (idx >= GG * 128) return;
  out[idx] = 0.6f * e0[idx] + 0.4f * e1[idx];
}

// =====================================================================
extern "C" void kernel_launch(void* const* d_in, const int* in_sizes, int n_in,
                              void* d_out, int out_size, void* d_ws, size_t ws_size,
                              hipStream_t stream) {
  const float* x = (const float*)d_in[0];
  const float* edge_attr = (const float*)d_in[1];
  const int* edge_index = (const int*)d_in[2];
  const int* batch = (const int*)d_in[3];
  const float* w0 = (const float*)d_in[4];
  const float* b0 = (const float*)d_in[5];
  const float* we0 = (const float*)d_in[6];
  const float* be0 = (const float*)d_in[7];
  const float* ln0_g = (const float*)d_in[8];
  const float* ln0_b = (const float*)d_in[9];
  const float* qkv_w = (const float*)d_in[10];
  const float* qkv_b = (const float*)d_in[11];
  const float* edge_w = (const float*)d_in[12];
  const float* skip_w = (const float*)d_in[13];
  const float* skip_b = (const float*)d_in[14];
  const float* up_w = (const float*)d_in[15];
  const float* up_b = (const float*)d_in[16];
  const float* ng = (const float*)d_in[17];
  const float* nbeta = (const float*)d_in[18];
  const float* sag_wrel = (const float*)d_in[19];
  const float* sag_brel = (const float*)d_in[20];
  const float* sag_wroot = (const float*)d_in[21];
  const float* re_w = (const float*)d_in[22];
  const float* re_b = (const float*)d_in[23];
  const int* srcp = edge_index;
  const int* dstp = edge_index + EE;
  float* out = (float*)d_out;
  (void)in_sizes; (void)n_in;

  float* ws = (float*)d_ws;
  size_t o = 0;
  auto alloc = [&](size_t n) { n = (n + 3) & ~(size_t)3; float* p = ws + o; o += n; return p; };
  u16* h_hi = (u16*)alloc((size_t)NN * 64);
  u16* h_lo = (u16*)alloc((size_t)NN * 64);
  float* hn = alloc((size_t)NN * 128);
  u32* r_hi = (u32*)alloc((size_t)NN * 64);
  u32* r_lo = (u32*)alloc((size_t)NN * 64);
  u16* nodebuf = (u16*)alloc((size_t)NN * 256);   // NN x 512 bf16 (q|qe|kv)
  u16* ea = (u16*)alloc((size_t)EE * 32);         // EE x 64 bf16, dst-CSR order
  int* csr_src = (int*)alloc(EE);
  int* epos = (int*)alloc(EE);
  int* deg = (int*)alloc(NN);
  int* pre = (int*)alloc(NN);
  int* bsum = (int*)alloc(256);
  int* row_start = (int*)alloc(NN + 1);
  int* cursor = (int*)alloc(NN);
  int* out_start = (int*)alloc(NN + 1);
  int* gstart = (int*)alloc(GG + 1);
  int* sg_perm = (int*)alloc(EE);
  int* sg_start = (int*)alloc(GG + 1);
  float* gsum_in = alloc(GG * 64);
  float* W2 = alloc(64 * 128);
  float* bvec = alloc(128);
  u16* upfrag = (u16*)alloc(2048);
  u16* Wfrag_hi = (u16*)alloc(40960);
  u16* Wfrag_lo = (u16*)alloc(40960);
  u16* wef_hi = (u16*)alloc(4096);
  u16* wef_lo = (u16*)alloc(4096);
  u16* wef0_hi = (u16*)alloc(1024);
  u16* wef0_lo = (u16*)alloc(1024);
  unsigned* gm = (unsigned*)alloc(GG);
  float* gs = alloc(GG);
  float* gstat = alloc(2 * GG);
  float* gmean = alloc(GG);
  float* grstd = alloc(GG);
  float* WQE = alloc(128 * 128);
  float* bqe = alloc(128);
  float* ball = alloc(640);
  float* hrel = alloc(NN);
  float* troot = alloc(NN);
  float* sc = alloc(NN);
  float* scp = alloc(NN);
  float* embE = alloc(GG * 128);
  float* embs0 = alloc(GG * 128);
  float* embs1 = alloc(GG * 128);

  const size_t need = o * sizeof(float);
  if (ws_size < need) {
    hipMemsetAsync(d_out, 0, (size_t)out_size * sizeof(float), stream);
    return;
  }
  const int NSCAN = (NN + 255) / 256;  // 196

  auto gemm = [&](const float* A, const float* B, const float* bias, float* C,
                  int M, int Nn, int K, int act, int accum) {
    dim3 g((Nn + 63) / 64, (M + 63) / 64);
    gemm_kernel<<<g, 256, 0, stream>>>(A, B, bias, C, M, Nn, K, act, accum);
  };
  auto ex_scan = [&](const int* degp, int* startp, int* curp) {
    scan1<<<NSCAN, 256, 0, stream>>>(degp, pre, bsum, NN);
    scan2<<<1, 256, 0, stream>>>(bsum, NSCAN);
    scan3<<<NSCAN, 256, 0, stream>>>(pre, bsum, degp, startp, curp, NN);
  };
  auto tconv = [&](int il) {
    const float* wq = qkv_w + (size_t)(il * 3 + 0) * 128 * 128;
    const float* wk = qkv_w + (size_t)(il * 3 + 1) * 128 * 128;
    const float* wv = qkv_w + (size_t)(il * 3 + 2) * 128 * 128;
    const float* bq = qkv_b + (il * 3 + 0) * 128;
    const float* bk = qkv_b + (il * 3 + 1) * 128;
    const float* bv = qkv_b + (il * 3 + 2) * 128;
    const float* we = edge_w + (size_t)il * 64 * 128;
    const float* wsk = skip_w + (size_t)il * 128 * 128;
    const float* bsk = skip_b + il * 128;
    build_wqe<<<129, 128, 0, stream>>>(wq, bq, we, WQE, bqe);
    build_wfrag2<<<354, 256, 0, stream>>>(wq, wk, wv, WQE, wsk, we, bq, bk, bv, bqe, bsk,
                                          Wfrag_hi, Wfrag_lo, wef_hi, wef_lo, ball, gstat);
    dim3 ng2(10, (NN + 63) / 64);
    node_gemm<<<ng2, 256, 0, stream>>>(h_hi, h_lo, Wfrag_hi, Wfrag_lo, ball, nodebuf, hn);
    attn_node<<<NN / 4, 256, 0, stream>>>((const u32*)nodebuf, (const u32*)ea, row_start,
                                          csr_src, hn, r_hi, r_lo);
    bd_gemm<<<(NN / 16 + 3) / 4, 256, 0, stream>>>((const u16*)r_hi, (const u16*)r_lo,
                                                   wef_hi, wef_lo, hn, batch, gstat);
  };
  auto graph_ln_fast = [&](const float* gamma, const float* beta) {
    ln_final2<<<1, 256, 0, stream>>>(gstat, gstart, gmean, grstd);
    ln_apply<<<NN * 32 / 256, 256, 0, stream>>>(hn, h_hi, h_lo, batch, gmean, grstd, gamma, beta);
  };
  auto ea_mlp = [&](int il) {
    build_upfrag<<<16, 256, 0, stream>>>(up_w + (size_t)il * 4096, upfrag);
    edge_gemm<<<2048, 256, 0, stream>>>(ea, upfrag, up_b + il * 64);
  };

  // one-time topology structures
  hipMemsetAsync(deg, 0, NN * sizeof(int), stream);
  csr_hist<<<(EE + 255) / 256, 256, 0, stream>>>(dstp, deg);
  ex_scan(deg, row_start, cursor);
  gstart_build<<<(NN + 256) / 256, 256, 0, stream>>>(batch, gstart);
  csr_pos<<<(EE + 255) / 256, 256, 0, stream>>>(srcp, dstp, cursor, csr_src, epos);
  build_we0frag<<<8, 256, 0, stream>>>(we0, wef0_hi, wef0_lo);
  ea_enc_mfma<<<2048, 256, 0, stream>>>(edge_attr, wef0_hi, wef0_lo, be0, epos, ea);
  hipMemsetAsync(deg, 0, NN * sizeof(int), stream);
  out_hist<<<(EE + 255) / 256, 256, 0, stream>>>(csr_src, deg);
  ex_scan(deg, out_start, cursor);
  out_fill<<<(EE + 255) / 256, 256, 0, stream>>>(csr_src, cursor, sg_perm);
  sgstart_build<<<2, 256, 0, stream>>>(out_start, gstart, sg_start);
  // node encoder + first LN (classic stats path)
  gemm(x, w0, b0, hn, NN, 128, 64, 0, 0);
  ln_stats_block<<<GG, 256, 0, stream>>>(hn, gstart, gmean, grstd);
  ln_apply<<<NN * 32 / 256, 256, 0, stream>>>(hn, h_hi, h_lo, batch, gmean, grstd, ln0_g, ln0_b);

  for (int i = 0; i < 2; ++i) {
    tconv(i * 2 + 0);
    graph_ln_fast(ng + (i * 2) * 128, nbeta + (i * 2) * 128);
    ea_mlp(i * 2);
    tconv(i * 2 + 1);
    // SAG pooling on pre-LN conv2 output hn; edge emb via linearity
    build_w2<<<64, 256, 0, stream>>>(up_w + (size_t)(i * 2 + 1) * 4096,
                                     up_b + (i * 2 + 1) * 64,
                                     re_w + (size_t)i * 64 * 128, W2, bvec, gsum_in);
    dim3 gsg(GG, 16);
    gsum_pre<<<gsg, 256, 0, stream>>>(ea, sg_start, sg_perm, gsum_in);
    if (i == 0) ea_mlp(i * 2 + 1);  // ea after last SAG is never consumed
    node_dots<<<NN / 4, 256, 0, stream>>>(hn, sag_wrel + i * 128, sag_wroot + i * 128,
                                          hrel, troot, gm, gs);
    sag_gather<<<(NN + 255) / 256, 256, 0, stream>>>(hrel, troot, sag_brel + i, row_start,
                                                     csr_src, batch, sc, gm);
    sag_exp<<<(NN + 255) / 256, 256, 0, stream>>>(sc, batch, gm, gs, scp);
    emb_e_kernel<<<GG, 128, 0, stream>>>(gsum_in, sg_start, W2, bvec, re_b + i * 128, embE);
    emb_block<<<GG, 128, 0, stream>>>(hn, scp, gs, gstart, embE, i == 0 ? embs0 : embs1);
    if (i == 0) graph_ln_fast(ng + (i * 2 + 1) * 128, nbeta + (i * 2 + 1) * 128);
  }
  final_combine<<<GG * 128 / 256, 256, 0, stream>>>(embs0, embs1, out);
}

// Round 11
// 1755.109 us; speedup vs baseline: 1.1898x; 1.1898x over previous
//
#include <hip/hip_runtime.h>
#include <math.h>

#define NN 50000
#define EE 800000
#define GG 256

typedef unsigned short u16;
typedef unsigned int u32;
typedef __attribute__((ext_vector_type(4))) float f32x4;
typedef __attribute__((ext_vector_type(8))) short bf16x8;

__device__ __forceinline__ float elu_f(float x) { return x > 0.f ? x : expm1f(x); }

__device__ __forceinline__ unsigned fenc(float f) {
  unsigned b = __float_as_uint(f);
  return (b & 0x80000000u) ? ~b : (b | 0x80000000u);
}
__device__ __forceinline__ float fdec(unsigned u) {
  return __uint_as_float((u & 0x80000000u) ? (u ^ 0x80000000u) : ~u);
}
__device__ __forceinline__ u16 f2b(float f) {
  u32 u = __float_as_uint(f);
  u32 r = (u + 0x7fffu + ((u >> 16) & 1u)) >> 16;
  return (u16)r;
}
__device__ __forceinline__ float bf2f(u16 u) { return __uint_as_float(((u32)u) << 16); }
__device__ __forceinline__ float lo2f(u32 p) { return __uint_as_float(p << 16); }
__device__ __forceinline__ float hi2f(u32 p) { return __uint_as_float(p & 0xffff0000u); }

__device__ __forceinline__ float wred64(float v) {
#pragma unroll
  for (int m = 32; m; m >>= 1) v += __shfl_xor(v, m, 64);
  return v;
}

// ---------------- generic tiled f32 GEMM: C = act(A@B + bias (+C)) ----------------
__global__ __launch_bounds__(256) void gemm_kernel(
    const float* __restrict__ A, const float* __restrict__ B,
    const float* __restrict__ bias, float* __restrict__ C,
    int M, int Nn, int K, int act, int accum) {
  __shared__ float As[16][68];
  __shared__ float Bs[16][68];
  const int bm = blockIdx.y * 64;
  const int bn = blockIdx.x * 64;
  const int tid = threadIdx.x;
  const int tx = tid & 15, ty = tid >> 4;
  const int lr = tid >> 2;
  const int lk = (tid & 3) << 2;
  float acc[4][4] = {};
  for (int k0 = 0; k0 < K; k0 += 16) {
    int arow = bm + lr;
    float4 a4 = {0.f, 0.f, 0.f, 0.f};
    if (arow < M) a4 = *reinterpret_cast<const float4*>(A + (size_t)arow * K + k0 + lk);
    As[lk + 0][lr] = a4.x; As[lk + 1][lr] = a4.y;
    As[lk + 2][lr] = a4.z; As[lk + 3][lr] = a4.w;
    float4 b4 = *reinterpret_cast<const float4*>(B + (size_t)(k0 + ty) * Nn + bn + tx * 4);
    *reinterpret_cast<float4*>(&Bs[ty][tx * 4]) = b4;
    __syncthreads();
#pragma unroll
    for (int kk = 0; kk < 16; ++kk) {
      float4 av = *reinterpret_cast<const float4*>(&As[kk][ty * 4]);
      float4 bv = *reinterpret_cast<const float4*>(&Bs[kk][tx * 4]);
      float a_[4] = {av.x, av.y, av.z, av.w};
      float b_[4] = {bv.x, bv.y, bv.z, bv.w};
#pragma unroll
      for (int ii = 0; ii < 4; ++ii)
#pragma unroll
        for (int jj = 0; jj < 4; ++jj)
          acc[ii][jj] = fmaf(a_[ii], b_[jj], acc[ii][jj]);
    }
    __syncthreads();
  }
#pragma unroll
  for (int ii = 0; ii < 4; ++ii) {
    int row = bm + ty * 4 + ii;
    if (row >= M) continue;
#pragma unroll
    for (int jj = 0; jj < 4; ++jj) {
      int col = bn + tx * 4 + jj;
      float val = acc[ii][jj];
      if (bias) val += bias[col];
      if (accum) val += C[(size_t)row * Nn + col];
      if (act) val = elu_f(val);
      C[(size_t)row * Nn + col] = val;
    }
  }
}

// ---------------- CSR build ----------------
__global__ void csr_hist(const int* __restrict__ dst, int* __restrict__ deg) {
  int e = blockIdx.x * blockDim.x + threadIdx.x;
  if (e < EE) atomicAdd(&deg[dst[e]], 1);
}

__global__ void scan1(const int* __restrict__ deg, int* __restrict__ pre,
                      int* __restrict__ bsum, int n) {
  __shared__ int s[256];
  int t = threadIdx.x;
  int i = blockIdx.x * 256 + t;
  int v = (i < n) ? deg[i] : 0;
  s[t] = v;
  __syncthreads();
  for (int off = 1; off < 256; off <<= 1) {
    int tmp = (t >= off) ? s[t - off] : 0;
    __syncthreads();
    s[t] += tmp;
    __syncthreads();
  }
  if (i < n) pre[i] = s[t] - v;
  if (t == 255) bsum[blockIdx.x] = s[255];
}

__global__ void scan2(int* __restrict__ bsum, int nb) {
  __shared__ int s[256];
  int t = threadIdx.x;
  int v = (t < nb) ? bsum[t] : 0;
  s[t] = v;
  __syncthreads();
  for (int off = 1; off < 256; off <<= 1) {
    int tmp = (t >= off) ? s[t - off] : 0;
    __syncthreads();
    s[t] += tmp;
    __syncthreads();
  }
  if (t < nb) bsum[t] = s[t] - v;
}

__global__ void scan3(const int* __restrict__ pre, const int* __restrict__ bsum,
                      const int* __restrict__ deg, int* __restrict__ row_start,
                      int* __restrict__ cursor, int n) {
  int i = blockIdx.x * 256 + threadIdx.x;
  if (i < n) {
    int v = pre[i] + bsum[blockIdx.x];
    row_start[i] = v;
    cursor[i] = v;
    if (i == n - 1) row_start[n] = v + deg[i];
  }
}

__global__ void gstart_build(const int* __restrict__ batch, int* __restrict__ gstart) {
  int n = blockIdx.x * blockDim.x + threadIdx.x;
  if (n > NN) return;
  int b = (n < NN) ? batch[n] : GG;
  int pb = (n == 0) ? -1 : batch[n - 1];
  for (int g = pb + 1; g <= b; ++g) gstart[g] = n;
}

__global__ void csr_pos(const int* __restrict__ src, const int* __restrict__ dst,
                        int* __restrict__ cursor, int* __restrict__ csr_src,
                        int* __restrict__ epos) {
  int e = blockIdx.x * blockDim.x + threadIdx.x;
  if (e >= EE) return;
  int pos = atomicAdd(&cursor[dst[e]], 1);
  csr_src[pos] = src[e];
  epos[e] = pos;
}

__global__ void out_hist(const int* __restrict__ csr_src, int* __restrict__ odeg) {
  int pos = blockIdx.x * blockDim.x + threadIdx.x;
  if (pos < EE) atomicAdd(&odeg[csr_src[pos]], 1);
}

__global__ void out_fill(const int* __restrict__ csr_src, int* __restrict__ ocursor,
                         int* __restrict__ operm) {
  int pos = blockIdx.x * blockDim.x + threadIdx.x;
  if (pos < EE) {
    int slot = atomicAdd(&ocursor[csr_src[pos]], 1);
    operm[slot] = pos;
  }
}

__global__ void sgstart_build(const int* __restrict__ out_start, const int* __restrict__ gstart,
                              int* __restrict__ sg_start) {
  int t = blockIdx.x * blockDim.x + threadIdx.x;
  if (t <= GG) sg_start[t] = out_start[gstart[t]];
}

// we0[16x64] -> split bf16 fragments, K padded to 32 (k>=16 -> 0)
__global__ void build_we0frag(const float* __restrict__ we0, u16* __restrict__ wf_hi,
                              u16* __restrict__ wf_lo) {
  int idx = blockIdx.x * 256 + threadIdx.x;  // 2048
  if (idx >= 2048) return;
  int j = idx & 7, lane = (idx >> 3) & 63, t = idx >> 9;
  int k = (lane >> 4) * 8 + j;
  int c = t * 16 + (lane & 15);
  float w = (k < 16) ? we0[(size_t)k * 64 + c] : 0.f;
  u16 hi = f2b(w);
  wf_hi[idx] = hi;
  wf_lo[idx] = f2b(w - bf2f(hi));
}

// MFMA edge encoder: ea[epos[e]] = elu(edge_attr[e] @ we0 + be0), 16 edges/wave
__global__ __launch_bounds__(256) void ea_enc_mfma(const float* __restrict__ edge_attr,
                                                   const u16* __restrict__ wf_hi,
                                                   const u16* __restrict__ wf_lo,
                                                   const float* __restrict__ be0,
                                                   const int* __restrict__ epos,
                                                   u16* __restrict__ ea) {
  int lane = threadIdx.x & 63;
  int gwave = (blockIdx.x * 256 + threadIdx.x) >> 6;
  int nwaves = (gridDim.x * 256) >> 6;
  bf16x8 bh[4], bl[4];
#pragma unroll
  for (int t = 0; t < 4; ++t) {
    bh[t] = *reinterpret_cast<const bf16x8*>(wf_hi + ((size_t)(t * 64 + lane)) * 8);
    bl[t] = *reinterpret_cast<const bf16x8*>(wf_lo + ((size_t)(t * 64 + lane)) * 8);
  }
  float bias_c[4];
#pragma unroll
  for (int t = 0; t < 4; ++t) bias_c[t] = be0[t * 16 + (lane & 15)];
  const int rif = lane & 15;
  const int kg = lane >> 4;
  for (int mt = gwave; mt < EE / 16; mt += nwaves) {
    int base = mt * 16;
    bf16x8 ah = {}, al = {};
    if (kg < 2) {
      const float* ap = edge_attr + (size_t)(base + rif) * 16 + kg * 8;
      float4 f0 = *reinterpret_cast<const float4*>(ap);
      float4 f1 = *reinterpret_cast<const float4*>(ap + 4);
      float fv[8] = {f0.x, f0.y, f0.z, f0.w, f1.x, f1.y, f1.z, f1.w};
#pragma unroll
      for (int jj = 0; jj < 8; ++jj) {
        u16 hi = f2b(fv[jj]);
        ah[jj] = (short)hi;
        al[jj] = (short)f2b(fv[jj] - bf2f(hi));
      }
    }
    f32x4 acc[4] = {};
#pragma unroll
    for (int t = 0; t < 4; ++t) {
      acc[t] = __builtin_amdgcn_mfma_f32_16x16x32_bf16(ah, bh[t], acc[t], 0, 0, 0);
      acc[t] = __builtin_amdgcn_mfma_f32_16x16x32_bf16(ah, bl[t], acc[t], 0, 0, 0);
      acc[t] = __builtin_amdgcn_mfma_f32_16x16x32_bf16(al, bh[t], acc[t], 0, 0, 0);
    }
#pragma unroll
    for (int rg = 0; rg < 4; ++rg) {
      int pr = epos[base + kg * 4 + rg];
#pragma unroll
      for (int t = 0; t < 4; ++t)
        ea[(size_t)pr * 64 + t * 16 + rif] = f2b(elu_f(acc[t][rg] + bias_c[t]));
    }
  }
}

// ---------------- graph LayerNorm ----------------
__global__ __launch_bounds__(256) void ln_stats_block(const float* __restrict__ h,
                                                      const int* __restrict__ gstart,
                                                      float* __restrict__ gmean,
                                                      float* __restrict__ grstd) {
  __shared__ float ls[4], lss[4];
  int g = blockIdx.x, t = threadIdx.x;
  int n0 = gstart[g], n1 = gstart[g + 1];
  int total4 = (n1 - n0) * 32;
  const float4* base = (const float4*)(h + (size_t)n0 * 128);
  float s = 0.f, ss = 0.f;
  for (int i = t; i < total4; i += 256) {
    float4 v = base[i];
    s += v.x + v.y + v.z + v.w;
    ss += v.x * v.x + v.y * v.y + v.z * v.z + v.w * v.w;
  }
  s = wred64(s);
  ss = wred64(ss);
  if ((t & 63) == 0) { ls[t >> 6] = s; lss[t >> 6] = ss; }
  __syncthreads();
  if (t == 0) {
    float S = ls[0] + ls[1] + ls[2] + ls[3];
    float SS = lss[0] + lss[1] + lss[2] + lss[3];
    float cnt = fmaxf((float)(n1 - n0) * 128.f, 1.0f);
    float mean = S / cnt;
    float var = fmaxf(SS / cnt - mean * mean, 0.f);
    gmean[g] = mean;
    grstd[g] = rsqrtf(var + 1e-5f);
  }
}

// LN apply -> split bf16 (hi + lo residual)
__global__ __launch_bounds__(256) void ln_apply(const float* __restrict__ in,
                                                u16* __restrict__ out_hi,
                                                u16* __restrict__ out_lo,
                                                const int* __restrict__ batch,
                                                const float* __restrict__ gmean,
                                                const float* __restrict__ grstd,
                                                const float* __restrict__ gamma,
                                                const float* __restrict__ beta) {
  int idx = blockIdx.x * blockDim.x + threadIdx.x;
  if (idx >= NN * 32) return;
  int n = idx >> 5, c4 = (idx & 31) * 4;
  int g = batch[n];
  float mean = gmean[g], rstd = grstd[g];
  float4 xv = *reinterpret_cast<const float4*>(in + (size_t)n * 128 + c4);
  float4 gv = *reinterpret_cast<const float4*>(gamma + c4);
  float4 bv = *reinterpret_cast<const float4*>(beta + c4);
  float v0 = elu_f((xv.x - mean) * rstd * gv.x + bv.x);
  float v1 = elu_f((xv.y - mean) * rstd * gv.y + bv.y);
  float v2 = elu_f((xv.z - mean) * rstd * gv.z + bv.z);
  float v3 = elu_f((xv.w - mean) * rstd * gv.w + bv.w);
  u16 h0 = f2b(v0), h1 = f2b(v1), h2 = f2b(v2), h3 = f2b(v3);
  uint2 hi = {(u32)h0 | ((u32)h1 << 16), (u32)h2 | ((u32)h3 << 16)};
  uint2 lo = {(u32)f2b(v0 - bf2f(h0)) | ((u32)f2b(v1 - bf2f(h1)) << 16),
              (u32)f2b(v2 - bf2f(h2)) | ((u32)f2b(v3 - bf2f(h3)) << 16)};
  *reinterpret_cast<uint2*>(out_hi + (size_t)n * 128 + c4) = hi;
  *reinterpret_cast<uint2*>(out_lo + (size_t)n * 128 + c4) = lo;
}

// ---------------- per-layer weight transforms ----------------
__global__ void build_wqe(const float* __restrict__ wq, const float* __restrict__ bq,
                          const float* __restrict__ we, float* __restrict__ WQE,
                          float* __restrict__ bqe) {
  int col = threadIdx.x;
  int row = blockIdx.x;
  int hh = col >> 6, j = col & 63;
  const float* wrow = (row < 128) ? (wq + (size_t)row * 128) : bq;
  float acc = 0.f;
  for (int c = 0; c < 64; ++c) acc += wrow[hh * 64 + c] * we[(size_t)j * 128 + hh * 64 + c];
  if (row < 128) WQE[(size_t)row * 128 + col] = acc;
  else bqe[col] = acc;
}

// fused: Wfrag (hi/lo) + wef (hi/lo) + ball
__global__ void build_wfrag2(const float* __restrict__ wq, const float* __restrict__ wk,
                             const float* __restrict__ wv, const float* __restrict__ WQE,
                             const float* __restrict__ wsk, const float* __restrict__ we,
                             const float* __restrict__ bq, const float* __restrict__ bk,
                             const float* __restrict__ bv, const float* __restrict__ bqe,
                             const float* __restrict__ bsk,
                             u16* __restrict__ Wfrag_hi, u16* __restrict__ Wfrag_lo,
                             u16* __restrict__ wef_hi, u16* __restrict__ wef_lo,
                             float* __restrict__ ball) {
  int idx = blockIdx.x * 256 + threadIdx.x;
  if (idx < 81920) {
    int j = idx & 7, lane = (idx >> 3) & 63, rest = idx >> 9;
    int tg = rest % 40, s = rest / 40;
    int k = s * 32 + (lane >> 4) * 8 + j;
    int col = tg * 16 + (lane & 15);
    int sel = col >> 7, c = col & 127;
    const float* src = sel == 0 ? wq : sel == 1 ? wk : sel == 2 ? wv : sel == 3 ? WQE : wsk;
    float w = src[(size_t)k * 128 + c];
    u16 hi = f2b(w);
    Wfrag_hi[idx] = hi;
    Wfrag_lo[idx] = f2b(w - bf2f(hi));
  } else if (idx < 90112) {
    int i2 = idx - 81920;
    int j = i2 & 7, lane = (i2 >> 3) & 63, rest = i2 >> 9;
    int t = rest & 3, hh = (rest >> 2) & 1, s = rest >> 3;
    int k = s * 32 + (lane >> 4) * 8 + j;
    int col = hh * 64 + t * 16 + (lane & 15);
    float w = we[(size_t)k * 128 + col];
    u16 hi = f2b(w);
    wef_hi[i2] = hi;
    wef_lo[i2] = f2b(w - bf2f(hi));
  }
  if (idx < 640) {
    int sel = idx >> 7, c = idx & 127;
    const float* s2 = sel == 0 ? bq : sel == 1 ? bk : sel == 2 ? bv : sel == 3 ? bqe : bsk;
    ball[idx] = s2[c];
  }
}

// up[64x64] f32 -> bf16 fragments
__global__ void build_upfrag(const float* __restrict__ up, u16* __restrict__ upfrag) {
  int idx = blockIdx.x * 256 + threadIdx.x;
  if (idx >= 4096) return;
  int j = idx & 7, lane = (idx >> 3) & 63, st = idx >> 9;
  int s = st >> 2, t = st & 3;
  int k = s * 32 + (lane >> 4) * 8 + j;
  int c = t * 16 + (lane & 15);
  upfrag[idx] = f2b(up[k * 64 + c]);
}

// W2 = up @ re_w; bvec = ub @ re_w; also zero gsum_in (GG*64). Launch 64 blocks.
__global__ void build_w2(const float* __restrict__ up, const float* __restrict__ ub,
                         const float* __restrict__ re_w, float* __restrict__ W2,
                         float* __restrict__ bvec, float* __restrict__ gsum_in) {
  int idx = blockIdx.x * 256 + threadIdx.x;
  if (idx < 64 * 128) {
    int k_ = idx >> 7, c = idx & 127;
    float a = 0.f;
    for (int j = 0; j < 64; ++j) a = fmaf(up[k_ * 64 + j], re_w[j * 128 + c], a);
    W2[idx] = a;
  } else if (idx < 64 * 128 + 128) {
    int c = idx - 64 * 128;
    float a = 0.f;
    for (int j = 0; j < 64; ++j) a = fmaf(ub[j], re_w[j * 128 + c], a);
    bvec[c] = a;
  }
  if (idx < GG * 64) gsum_in[idx] = 0.f;
}

// ---------------- split-precision MFMA node GEMM ----------------
// nodebuf row layout (u16 idx): q[0..127] | qe[128..255] | kv interleaved [256..511]
__global__ __launch_bounds__(256) void node_gemm(const u16* __restrict__ h_hi,
                                                 const u16* __restrict__ h_lo,
                                                 const u16* __restrict__ Wfrag_hi,
                                                 const u16* __restrict__ Wfrag_lo,
                                                 const float* __restrict__ ball,
                                                 u16* __restrict__ nodebuf,
                                                 float* __restrict__ hn) {
  int tid = threadIdx.x;
  int lane = tid & 63;
  int wv = tid >> 6;
  int cb = blockIdx.x;
  int rbase = blockIdx.y * 64 + wv * 16;
  int rif = lane & 15, kg = lane >> 4;
  f32x4 acc[4] = {};
  int arow = rbase + rif;
  bool rowok = arow < NN;
  const u16* aph = h_hi + (size_t)arow * 128 + kg * 8;
  const u16* apl = h_lo + (size_t)arow * 128 + kg * 8;
#pragma unroll
  for (int s = 0; s < 4; ++s) {
    bf16x8 ah = {}, al = {};
    if (rowok) {
      ah = *reinterpret_cast<const bf16x8*>(aph + s * 32);
      al = *reinterpret_cast<const bf16x8*>(apl + s * 32);
    }
#pragma unroll
    for (int t = 0; t < 4; ++t) {
      size_t fo = ((size_t)((s * 40 + cb * 4 + t) * 64 + lane)) * 8;
      bf16x8 bh = *reinterpret_cast<const bf16x8*>(Wfrag_hi + fo);
      bf16x8 bl = *reinterpret_cast<const bf16x8*>(Wfrag_lo + fo);
      acc[t] = __builtin_amdgcn_mfma_f32_16x16x32_bf16(ah, bh, acc[t], 0, 0, 0);
      acc[t] = __builtin_amdgcn_mfma_f32_16x16x32_bf16(ah, bl, acc[t], 0, 0, 0);
      acc[t] = __builtin_amdgcn_mfma_f32_16x16x32_bf16(al, bh, acc[t], 0, 0, 0);
    }
  }
#pragma unroll
  for (int t = 0; t < 4; ++t) {
    int col = (cb * 4 + t) * 16 + rif;
    float bia = ball[col];
#pragma unroll
    for (int rg = 0; rg < 4; ++rg) {
      int row = rbase + kg * 4 + rg;
      if (row < NN) {
        float val = acc[t][rg] + bia;
        if (col < 512) {
          int idx;
          if (col < 128) idx = col;
          else if (col < 256) { int c1 = col - 128; idx = 256 + ((c1 >> 1) << 2) + (c1 & 1); }
          else if (col < 384) { int c2 = col - 256; idx = 256 + ((c2 >> 1) << 2) + 2 + (c2 & 1); }
          else idx = 128 + (col - 384);
          nodebuf[(size_t)row * 512 + idx] = f2b(val);
        } else {
          hn[(size_t)row * 128 + col - 512] = val;
        }
      }
    }
  }
}

// ---------------- MFMA edge GEMM: ea = elu(ea @ up + ub), in place ----------------
__global__ __launch_bounds__(256) void edge_gemm(u16* __restrict__ ea,
                                                 const u16* __restrict__ upfrag,
                                                 const float* __restrict__ ub) {
  int lane = threadIdx.x & 63;
  int gwave = (blockIdx.x * 256 + threadIdx.x) >> 6;
  int nwaves = (gridDim.x * 256) >> 6;
  bf16x8 bfrag[2][4];
#pragma unroll
  for (int s = 0; s < 2; ++s)
#pragma unroll
    for (int t = 0; t < 4; ++t)
      bfrag[s][t] = *reinterpret_cast<const bf16x8*>(upfrag + ((size_t)((s * 4 + t) * 64 + lane)) * 8);
  float bias_c[4];
#pragma unroll
  for (int t = 0; t < 4; ++t) bias_c[t] = ub[t * 16 + (lane & 15)];
  const int rif = lane & 15;
  const int kg = lane >> 4;
  for (int mt = gwave; mt < EE / 16; mt += nwaves) {
    size_t rowbase = (size_t)mt * 16;
    const u16* arow = ea + (rowbase + rif) * 64;
    bf16x8 a0 = *reinterpret_cast<const bf16x8*>(arow + kg * 8);
    bf16x8 a1 = *reinterpret_cast<const bf16x8*>(arow + 32 + kg * 8);
    f32x4 acc[4] = {};
#pragma unroll
    for (int t = 0; t < 4; ++t) {
      acc[t] = __builtin_amdgcn_mfma_f32_16x16x32_bf16(a0, bfrag[0][t], acc[t], 0, 0, 0);
      acc[t] = __builtin_amdgcn_mfma_f32_16x16x32_bf16(a1, bfrag[1][t], acc[t], 0, 0, 0);
    }
#pragma unroll
    for (int t = 0; t < 4; ++t)
#pragma unroll
      for (int rg = 0; rg < 4; ++rg) {
        float val = acc[t][rg] + bias_c[t];
        ea[(rowbase + kg * 4 + rg) * 64 + t * 16 + rif] = f2b(elu_f(val));
      }
  }
}

// ---------------- split-precision MFMA BD GEMM: hn += r @ BD (per-head we) ----------------
__global__ __launch_bounds__(256) void bd_gemm(const u16* __restrict__ r_hi,
                                               const u16* __restrict__ r_lo,
                                               const u16* __restrict__ wef_hi,
                                               const u16* __restrict__ wef_lo,
                                               float* __restrict__ hn) {
  int tid = threadIdx.x;
  int lane = tid & 63;
  int w = blockIdx.x * 4 + (tid >> 6);
  if (w >= NN / 16) return;
  int rif = lane & 15, kg = lane >> 4;
  size_t rowbase = (size_t)w * 16;
  const u16* ahb = r_hi + (rowbase + rif) * 128;
  const u16* alb = r_lo + (rowbase + rif) * 128;
  f32x4 acc[2][4] = {};
#pragma unroll
  for (int hh = 0; hh < 2; ++hh)
#pragma unroll
    for (int s = 0; s < 2; ++s) {
      int ko = hh * 64 + s * 32 + kg * 8;
      bf16x8 ah = *reinterpret_cast<const bf16x8*>(ahb + ko);
      bf16x8 al = *reinterpret_cast<const bf16x8*>(alb + ko);
#pragma unroll
      for (int t = 0; t < 4; ++t) {
        size_t fo = ((size_t)((((s * 2 + hh) * 4 + t)) * 64 + lane)) * 8;
        bf16x8 bh = *reinterpret_cast<const bf16x8*>(wef_hi + fo);
        bf16x8 bl = *reinterpret_cast<const bf16x8*>(wef_lo + fo);
        acc[hh][t] = __builtin_amdgcn_mfma_f32_16x16x32_bf16(ah, bh, acc[hh][t], 0, 0, 0);
        acc[hh][t] = __builtin_amdgcn_mfma_f32_16x16x32_bf16(ah, bl, acc[hh][t], 0, 0, 0);
        acc[hh][t] = __builtin_amdgcn_mfma_f32_16x16x32_bf16(al, bh, acc[hh][t], 0, 0, 0);
      }
    }
#pragma unroll
  for (int hh = 0; hh < 2; ++hh)
#pragma unroll
    for (int t = 0; t < 4; ++t)
#pragma unroll
      for (int rg = 0; rg < 4; ++rg) {
        size_t row = rowbase + kg * 4 + rg;
        int col = hh * 64 + t * 16 + rif;
        hn[row * 128 + col] += acc[hh][t][rg];
      }
}

// per-src-graph sum of current ea rows, chunked + atomic merge
__global__ __launch_bounds__(256) void gsum_pre(const u16* __restrict__ ea,
                                                const int* __restrict__ sg_start,
                                                const int* __restrict__ sg_perm,
                                                float* __restrict__ gsum_in) {
  __shared__ float red[8][64];
  int g = blockIdx.x, t = threadIdx.x;
  int c2 = t & 31;
  int rgrp = t >> 5;
  int gr = blockIdx.y * 8 + rgrp;
  int p0 = sg_start[g], p1 = sg_start[g + 1];
  float slo = 0.f, shi = 0.f;
  for (int i = p0 + gr; i < p1; i += 128) {
    int pos = sg_perm[i];
    u32 w = ((const u32*)ea)[(size_t)pos * 32 + c2];
    slo += lo2f(w);
    shi += hi2f(w);
  }
  red[rgrp][c2 * 2] = slo;
  red[rgrp][c2 * 2 + 1] = shi;
  __syncthreads();
  if (t < 64) {
    float a = 0.f;
#pragma unroll
    for (int rr = 0; rr < 8; ++rr) a += red[rr][t];
    atomicAdd(&gsum_in[(size_t)g * 64 + t], a);
  }
}

// embE = elu(gsum_in @ W2 + cnt*bvec + re_b)
__global__ void emb_e_kernel(const float* __restrict__ gsum_in, const int* __restrict__ sg_start,
                             const float* __restrict__ W2, const float* __restrict__ bvec,
                             const float* __restrict__ re_b, float* __restrict__ embE) {
  int g = blockIdx.x, c = threadIdx.x;
  float cnt = (float)(sg_start[g + 1] - sg_start[g]);
  float a = re_b[c] + cnt * bvec[c];
  for (int k_ = 0; k_ < 64; ++k_) a = fmaf(gsum_in[(size_t)g * 64 + k_], W2[k_ * 128 + c], a);
  embE[(size_t)g * 128 + c] = elu_f(a);
}

// ---------------- fused flash attention: one wave per dst, 2 edges/wave ----------------
// lanes 0-31: edge A, lanes 32-63: edge B; each lane owns 4 channels.
__global__ __launch_bounds__(256) void attn_node(const u32* __restrict__ nb32,
                                                 const u32* __restrict__ ea32,
                                                 const int* __restrict__ row_start,
                                                 const int* __restrict__ csr_src,
                                                 float* __restrict__ hn,
                                                 u32* __restrict__ r_hi,
                                                 u32* __restrict__ r_lo) {
  int d = (blockIdx.x * blockDim.x + threadIdx.x) >> 6;
  if (d >= NN) return;
  int lane = threadIdx.x & 63;
  int half = lane >> 5;
  int l = lane & 31;
  int li = l & 15;
  int qi = (l >> 4) * 32 + li * 2;  // u32 channel-pair index (0..63)
  int p0 = row_start[d], p1 = row_start[d + 1];
  if (p0 == p1) {
    if (!half) {
      uint2 z = {0u, 0u};
      *reinterpret_cast<uint2*>(r_hi + (size_t)d * 64 + qi) = z;
      *reinterpret_cast<uint2*>(r_lo + (size_t)d * 64 + qi) = z;
    }
    return;
  }
  size_t dbase = (size_t)d * 256;
  uint2 qp = *reinterpret_cast<const uint2*>(nb32 + dbase + qi);
  uint2 qep = *reinterpret_cast<const uint2*>(nb32 + dbase + 64 + qi);
  float q0 = lo2f(qp.x), q1 = hi2f(qp.x), q2 = lo2f(qp.y), q3 = hi2f(qp.y);
  float g0 = lo2f(qep.x), g1 = hi2f(qep.x), g2 = lo2f(qep.y), g3 = hi2f(qep.y);
  int cnt = p1 - p0;
  int nIter = (cnt + 1) >> 1;
  float m = -3.4e38f, ss = 0.f;
  float a0 = 0.f, a1 = 0.f, a2 = 0.f, a3 = 0.f;
  float r0 = 0.f, r1 = 0.f, r2 = 0.f, r3 = 0.f;
  int i = half;
  bool vld = i < cnt;
  int pc = vld ? p0 + i : p0;
  int sc = csr_src[pc];
  uint4 kv = *reinterpret_cast<const uint4*>(nb32 + (size_t)sc * 256 + 128 + qi * 2);
  uint2 ev = *reinterpret_cast<const uint2*>(ea32 + (size_t)pc * 32 + li * 2);
  for (int j = 0; j < nIter; ++j) {
    int i2 = i + 2;
    bool nvld = i2 < cnt;
    int pn = nvld ? p0 + i2 : p0;
    int sn = csr_src[pn];
    uint4 kvn = *reinterpret_cast<const uint4*>(nb32 + (size_t)sn * 256 + 128 + qi * 2);
    uint2 evn = *reinterpret_cast<const uint2*>(ea32 + (size_t)pn * 32 + li * 2);
    float x0 = lo2f(ev.x), x1 = hi2f(ev.x), x2 = lo2f(ev.y), x3 = hi2f(ev.y);
    float p = q0 * lo2f(kv.x) + q1 * hi2f(kv.x) + q2 * lo2f(kv.z) + q3 * hi2f(kv.z) +
              g0 * x0 + g1 * x1 + g2 * x2 + g3 * x3;
#pragma unroll
    for (int mm = 1; mm <= 8; mm <<= 1) p += __shfl_xor(p, mm, 64);  // per-16-lane head sum
    float lg = vld ? p * 0.125f : -3.4e38f;
    float mn = fmaxf(m, lg);
    float f = __expf(m - mn), w = __expf(lg - mn);
    ss = ss * f + w;
    a0 = a0 * f + w * lo2f(kv.y); a1 = a1 * f + w * hi2f(kv.y);
    a2 = a2 * f + w * lo2f(kv.w); a3 = a3 * f + w * hi2f(kv.w);
    r0 = r0 * f + w * x0; r1 = r1 * f + w * x1;
    r2 = r2 * f + w * x2; r3 = r3 * f + w * x3;
    m = mn;
    i = i2; vld = nvld; kv = kvn; ev = evn;
  }
  // merge edge-halves
  float mo = __shfl_xor(m, 32, 64);
  float so = __shfl_xor(ss, 32, 64);
  float b0 = __shfl_xor(a0, 32, 64), b1 = __shfl_xor(a1, 32, 64);
  float b2 = __shfl_xor(a2, 32, 64), b3 = __shfl_xor(a3, 32, 64);
  float t0 = __shfl_xor(r0, 32, 64), t1 = __shfl_xor(r1, 32, 64);
  float t2 = __shfl_xor(r2, 32, 64), t3 = __shfl_xor(r3, 32, 64);
  float mn = fmaxf(m, mo);
  float fs = __expf(m - mn), fo = __expf(mo - mn);
  ss = ss * fs + so * fo;
  a0 = a0 * fs + b0 * fo; a1 = a1 * fs + b1 * fo;
  a2 = a2 * fs + b2 * fo; a3 = a3 * fs + b3 * fo;
  r0 = r0 * fs + t0 * fo; r1 = r1 * fs + t1 * fo;
  r2 = r2 * fs + t2 * fo; r3 = r3 * fs + t3 * fo;
  if (!half) {
    float inv = 1.f / ss;
    int ch0 = (l >> 4) * 64 + li * 4;
    float* hp = hn + (size_t)d * 128 + ch0;
    float4 hv = *reinterpret_cast<float4*>(hp);
    hv.x += a0 * inv; hv.y += a1 * inv; hv.z += a2 * inv; hv.w += a3 * inv;
    *reinterpret_cast<float4*>(hp) = hv;
    float rv0 = r0 * inv, rv1 = r1 * inv, rv2 = r2 * inv, rv3 = r3 * inv;
    u16 h0 = f2b(rv0), h1 = f2b(rv1), h2 = f2b(rv2), h3 = f2b(rv3);
    uint2 rh = {(u32)h0 | ((u32)h1 << 16), (u32)h2 | ((u32)h3 << 16)};
    uint2 rl = {(u32)f2b(rv0 - bf2f(h0)) | ((u32)f2b(rv1 - bf2f(h1)) << 16),
                (u32)f2b(rv2 - bf2f(h2)) | ((u32)f2b(rv3 - bf2f(h3)) << 16)};
    *reinterpret_cast<uint2*>(r_hi + (size_t)d * 64 + qi) = rh;
    *reinterpret_cast<uint2*>(r_lo + (size_t)d * 64 + qi) = rl;
  }
}

// ---------------- SAG pooling ----------------
__global__ __launch_bounds__(256) void node_dots(const float* __restrict__ hn,
                                                 const float* __restrict__ wrel,
                                                 const float* __restrict__ wroot,
                                                 float* __restrict__ hrel,
                                                 float* __restrict__ troot,
                                                 unsigned* __restrict__ gm,
                                                 float* __restrict__ gs) {
  int tid0 = blockIdx.x * blockDim.x + threadIdx.x;
  if (tid0 < GG) gm[tid0] = 0u;
  else if (tid0 < 2 * GG) gs[tid0 - GG] = 0.f;
  int n = tid0 >> 6;
  if (n >= NN) return;
  int lane = threadIdx.x & 63;
  float x0 = hn[(size_t)n * 128 + lane], x1 = hn[(size_t)n * 128 + 64 + lane];
  float tr = wred64(x0 * wrel[lane] + x1 * wrel[64 + lane]);
  float tt = wred64(x0 * wroot[lane] + x1 * wroot[64 + lane]);
  if (lane == 0) { hrel[n] = tr; troot[n] = tt; }
}

__global__ __launch_bounds__(256) void sag_gather(const float* __restrict__ hrel,
                                                  const float* __restrict__ troot,
                                                  const float* __restrict__ brel,
                                                  const int* __restrict__ row_start,
                                                  const int* __restrict__ csr_src,
                                                  const int* __restrict__ batch,
                                                  float* __restrict__ sc, unsigned* __restrict__ gm) {
  int n = blockIdx.x * blockDim.x + threadIdx.x;
  if (n >= NN) return;
  float s = 0.f;
  int p1 = row_start[n + 1];
  for (int pos = row_start[n]; pos < p1; ++pos) s += hrel[csr_src[pos]];
  float v = s + troot[n] + brel[0];
  sc[n] = v;
  atomicMax(&gm[batch[n]], fenc(v));
}

__global__ __launch_bounds__(256) void sag_exp(const float* __restrict__ sc,
                                               const int* __restrict__ batch,
                                               const unsigned* __restrict__ gm,
                                               float* __restrict__ gs, float* __restrict__ scp) {
  int n = blockIdx.x * blockDim.x + threadIdx.x;
  if (n >= NN) return;
  int g = batch[n];
  float p = __expf(sc[n] - fdec(gm[g]));
  scp[n] = p;
  atomicAdd(&gs[g], p);
}

__global__ void emb_block(const float* __restrict__ hn, const float* __restrict__ scp,
                          const float* __restrict__ gs, const int* __restrict__ gstart,
                          const float* __restrict__ embE, float* __restrict__ dstv) {
  __shared__ float part[2];
  int g = blockIdx.x, c = threadIdx.x;
  int n0 = gstart[g], n1 = gstart[g + 1];
  float invg = 1.f / gs[g];
  float acc = 0.f;
  for (int n = n0; n < n1; ++n) acc = fmaf(hn[(size_t)n * 128 + c], scp[n] * invg, acc);
  float val = acc * embE[(size_t)g * 128 + c];
  float sq = val * val;
#pragma unroll
  for (int mm = 32; mm; mm >>= 1) sq += __shfl_xor(sq, mm, 64);
  if ((c & 63) == 0) part[c >> 6] = sq;
  __syncthreads();
  float nrm = sqrtf(part[0] + part[1]);
  dstv[(size_t)g * 128 + c] = elu_f(val / fmaxf(nrm, 1e-12f));
}

__global__ void final_combine(const float* __restrict__ e0, const float* __restrict__ e1,
                              float* __restrict__ out) {
  int idx = blockIdx.x * blockDim.x + threadIdx.x;
  if (idx >= GG * 128) return;
  out[idx] = 0.6f * e0[idx] + 0.4f * e1[idx];
}

// =====================================================================
extern "C" void kernel_launch(void* const* d_in, const int* in_sizes, int n_in,
                              void* d_out, int out_size, void* d_ws, size_t ws_size,
                              hipStream_t stream) {
  const float* x = (const float*)d_in[0];
  const float* edge_attr = (const float*)d_in[1];
  const int* edge_index = (const int*)d_in[2];
  const int* batch = (const int*)d_in[3];
  const float* w0 = (const float*)d_in[4];
  const float* b0 = (const float*)d_in[5];
  const float* we0 = (const float*)d_in[6];
  const float* be0 = (const float*)d_in[7];
  const float* ln0_g = (const float*)d_in[8];
  const float* ln0_b = (const float*)d_in[9];
  const float* qkv_w = (const float*)d_in[10];
  const float* qkv_b = (const float*)d_in[11];
  const float* edge_w = (const float*)d_in[12];
  const float* skip_w = (const float*)d_in[13];
  const float* skip_b = (const float*)d_in[14];
  const float* up_w = (const float*)d_in[15];
  const float* up_b = (const float*)d_in[16];
  const float* ng = (const float*)d_in[17];
  const float* nbeta = (const float*)d_in[18];
  const float* sag_wrel = (const float*)d_in[19];
  const float* sag_brel = (const float*)d_in[20];
  const float* sag_wroot = (const float*)d_in[21];
  const float* re_w = (const float*)d_in[22];
  const float* re_b = (const float*)d_in[23];
  const int* srcp = edge_index;
  const int* dstp = edge_index + EE;
  float* out = (float*)d_out;
  (void)in_sizes; (void)n_in;

  float* ws = (float*)d_ws;
  size_t o = 0;
  auto alloc = [&](size_t n) { n = (n + 3) & ~(size_t)3; float* p = ws + o; o += n; return p; };
  u16* h_hi = (u16*)alloc((size_t)NN * 64);
  u16* h_lo = (u16*)alloc((size_t)NN * 64);
  float* hn = alloc((size_t)NN * 128);
  u32* r_hi = (u32*)alloc((size_t)NN * 64);
  u32* r_lo = (u32*)alloc((size_t)NN * 64);
  u16* nodebuf = (u16*)alloc((size_t)NN * 256);   // NN x 512 bf16 (q|qe|kv)
  u16* ea = (u16*)alloc((size_t)EE * 32);         // EE x 64 bf16, dst-CSR order
  int* csr_src = (int*)alloc(EE);
  int* epos = (int*)alloc(EE);
  int* deg = (int*)alloc(NN);
  int* pre = (int*)alloc(NN);
  int* bsum = (int*)alloc(256);
  int* row_start = (int*)alloc(NN + 1);
  int* cursor = (int*)alloc(NN);
  int* out_start = (int*)alloc(NN + 1);
  int* gstart = (int*)alloc(GG + 1);
  int* sg_perm = (int*)alloc(EE);
  int* sg_start = (int*)alloc(GG + 1);
  float* gsum_in = alloc(GG * 64);
  float* W2 = alloc(64 * 128);
  float* bvec = alloc(128);
  u16* upfrag = (u16*)alloc(2048);
  u16* Wfrag_hi = (u16*)alloc(40960);
  u16* Wfrag_lo = (u16*)alloc(40960);
  u16* wef_hi = (u16*)alloc(4096);
  u16* wef_lo = (u16*)alloc(4096);
  u16* wef0_hi = (u16*)alloc(1024);
  u16* wef0_lo = (u16*)alloc(1024);
  unsigned* gm = (unsigned*)alloc(GG);
  float* gs = alloc(GG);
  float* gmean = alloc(GG);
  float* grstd = alloc(GG);
  float* WQE = alloc(128 * 128);
  float* bqe = alloc(128);
  float* ball = alloc(640);
  float* hrel = alloc(NN);
  float* troot = alloc(NN);
  float* sc = alloc(NN);
  float* scp = alloc(NN);
  float* embE = alloc(GG * 128);
  float* embs0 = alloc(GG * 128);
  float* embs1 = alloc(GG * 128);

  const size_t need = o * sizeof(float);
  if (ws_size < need) {
    hipMemsetAsync(d_out, 0, (size_t)out_size * sizeof(float), stream);
    return;
  }
  const int NSCAN = (NN + 255) / 256;  // 196

  auto gemm = [&](const float* A, const float* B, const float* bias, float* C,
                  int M, int Nn, int K, int act, int accum) {
    dim3 g((Nn + 63) / 64, (M + 63) / 64);
    gemm_kernel<<<g, 256, 0, stream>>>(A, B, bias, C, M, Nn, K, act, accum);
  };
  auto ex_scan = [&](const int* degp, int* startp, int* curp) {
    scan1<<<NSCAN, 256, 0, stream>>>(degp, pre, bsum, NN);
    scan2<<<1, 256, 0, stream>>>(bsum, NSCAN);
    scan3<<<NSCAN, 256, 0, stream>>>(pre, bsum, degp, startp, curp, NN);
  };
  auto graph_ln = [&](const float* in, const float* gamma, const float* beta) {
    ln_stats_block<<<GG, 256, 0, stream>>>(in, gstart, gmean, grstd);
    ln_apply<<<NN * 32 / 256, 256, 0, stream>>>(in, h_hi, h_lo, batch, gmean, grstd, gamma, beta);
  };
  auto tconv = [&](int il) {
    const float* wq = qkv_w + (size_t)(il * 3 + 0) * 128 * 128;
    const float* wk = qkv_w + (size_t)(il * 3 + 1) * 128 * 128;
    const float* wv = qkv_w + (size_t)(il * 3 + 2) * 128 * 128;
    const float* bq = qkv_b + (il * 3 + 0) * 128;
    const float* bk = qkv_b + (il * 3 + 1) * 128;
    const float* bv = qkv_b + (il * 3 + 2) * 128;
    const float* we = edge_w + (size_t)il * 64 * 128;
    const float* wsk = skip_w + (size_t)il * 128 * 128;
    const float* bsk = skip_b + il * 128;
    build_wqe<<<129, 128, 0, stream>>>(wq, bq, we, WQE, bqe);
    build_wfrag2<<<352, 256, 0, stream>>>(wq, wk, wv, WQE, wsk, we, bq, bk, bv, bqe, bsk,
                                          Wfrag_hi, Wfrag_lo, wef_hi, wef_lo, ball);
    dim3 ng2(10, (NN + 63) / 64);
    node_gemm<<<ng2, 256, 0, stream>>>(h_hi, h_lo, Wfrag_hi, Wfrag_lo, ball, nodebuf, hn);
    attn_node<<<NN / 4, 256, 0, stream>>>((const u32*)nodebuf, (const u32*)ea, row_start,
                                          csr_src, hn, r_hi, r_lo);
    bd_gemm<<<(NN / 16 + 3) / 4, 256, 0, stream>>>((const u16*)r_hi, (const u16*)r_lo,
                                                   wef_hi, wef_lo, hn);
  };
  auto ea_mlp = [&](int il) {
    build_upfrag<<<16, 256, 0, stream>>>(up_w + (size_t)il * 4096, upfrag);
    edge_gemm<<<2048, 256, 0, stream>>>(ea, upfrag, up_b + il * 64);
  };

  // one-time topology structures
  hipMemsetAsync(deg, 0, NN * sizeof(int), stream);
  csr_hist<<<(EE + 255) / 256, 256, 0, stream>>>(dstp, deg);
  ex_scan(deg, row_start, cursor);
  gstart_build<<<(NN + 256) / 256, 256, 0, stream>>>(batch, gstart);
  csr_pos<<<(EE + 255) / 256, 256, 0, stream>>>(srcp, dstp, cursor, csr_src, epos);
  build_we0frag<<<8, 256, 0, stream>>>(we0, wef0_hi, wef0_lo);
  ea_enc_mfma<<<2048, 256, 0, stream>>>(edge_attr, wef0_hi, wef0_lo, be0, epos, ea);
  hipMemsetAsync(deg, 0, NN * sizeof(int), stream);
  out_hist<<<(EE + 255) / 256, 256, 0, stream>>>(csr_src, deg);
  ex_scan(deg, out_start, cursor);
  out_fill<<<(EE + 255) / 256, 256, 0, stream>>>(csr_src, cursor, sg_perm);
  sgstart_build<<<2, 256, 0, stream>>>(out_start, gstart, sg_start);
  // node encoder + first LN
  gemm(x, w0, b0, hn, NN, 128, 64, 0, 0);
  graph_ln(hn, ln0_g, ln0_b);

  for (int i = 0; i < 2; ++i) {
    tconv(i * 2 + 0);
    graph_ln(hn, ng + (i * 2) * 128, nbeta + (i * 2) * 128);
    ea_mlp(i * 2);
    tconv(i * 2 + 1);
    // SAG pooling on pre-LN conv2 output hn; edge emb via linearity
    build_w2<<<64, 256, 0, stream>>>(up_w + (size_t)(i * 2 + 1) * 4096,
                                     up_b + (i * 2 + 1) * 64,
                                     re_w + (size_t)i * 64 * 128, W2, bvec, gsum_in);
    dim3 gsg(GG, 16);
    gsum_pre<<<gsg, 256, 0, stream>>>(ea, sg_start, sg_perm, gsum_in);
    if (i == 0) ea_mlp(i * 2 + 1);  // ea after last SAG is never consumed
    node_dots<<<NN / 4, 256, 0, stream>>>(hn, sag_wrel + i * 128, sag_wroot + i * 128,
                                          hrel, troot, gm, gs);
    sag_gather<<<(NN + 255) / 256, 256, 0, stream>>>(hrel, troot, sag_brel + i, row_start,
                                                     csr_src, batch, sc, gm);
    sag_exp<<<(NN + 255) / 256, 256, 0, stream>>>(sc, batch, gm, gs, scp);
    emb_e_kernel<<<GG, 128, 0, stream>>>(gsum_in, sg_start, W2, bvec, re_b + i * 128, embE);
    emb_block<<<GG, 128, 0, stream>>>(hn, scp, gs, gstart, embE, i == 0 ? embs0 : embs1);
    if (i == 0) graph_ln(hn, ng + (i * 2 + 1) * 128, nbeta + (i * 2 + 1) * 128);
  }
  final_combine<<<GG * 128 / 256, 256, 0, stream>>>(embs0, embs1, out);
}

// Round 12
// 1752.093 us; speedup vs baseline: 1.1919x; 1.0017x over previous
//
#include <hip/hip_runtime.h>
#include <math.h>

#define NN 50000
#define EE 800000
#define GG 256

typedef unsigned short u16;
typedef unsigned int u32;
typedef __attribute__((ext_vector_type(4))) float f32x4;
typedef __attribute__((ext_vector_type(8))) short bf16x8;

__device__ __forceinline__ float elu_f(float x) { return x > 0.f ? x : expm1f(x); }

__device__ __forceinline__ unsigned fenc(float f) {
  unsigned b = __float_as_uint(f);
  return (b & 0x80000000u) ? ~b : (b | 0x80000000u);
}
__device__ __forceinline__ float fdec(unsigned u) {
  return __uint_as_float((u & 0x80000000u) ? (u ^ 0x80000000u) : ~u);
}
__device__ __forceinline__ u16 f2b(float f) {
  u32 u = __float_as_uint(f);
  u32 r = (u + 0x7fffu + ((u >> 16) & 1u)) >> 16;
  return (u16)r;
}
__device__ __forceinline__ float bf2f(u16 u) { return __uint_as_float(((u32)u) << 16); }
__device__ __forceinline__ float lo2f(u32 p) { return __uint_as_float(p << 16); }
__device__ __forceinline__ float hi2f(u32 p) { return __uint_as_float(p & 0xffff0000u); }

__device__ __forceinline__ float wred64(float v) {
#pragma unroll
  for (int m = 32; m; m >>= 1) v += __shfl_xor(v, m, 64);
  return v;
}

// ---------------- generic tiled f32 GEMM: C = act(A@B + bias (+C)) ----------------
__global__ __launch_bounds__(256) void gemm_kernel(
    const float* __restrict__ A, const float* __restrict__ B,
    const float* __restrict__ bias, float* __restrict__ C,
    int M, int Nn, int K, int act, int accum) {
  __shared__ float As[16][68];
  __shared__ float Bs[16][68];
  const int bm = blockIdx.y * 64;
  const int bn = blockIdx.x * 64;
  const int tid = threadIdx.x;
  const int tx = tid & 15, ty = tid >> 4;
  const int lr = tid >> 2;
  const int lk = (tid & 3) << 2;
  float acc[4][4] = {};
  for (int k0 = 0; k0 < K; k0 += 16) {
    int arow = bm + lr;
    float4 a4 = {0.f, 0.f, 0.f, 0.f};
    if (arow < M) a4 = *reinterpret_cast<const float4*>(A + (size_t)arow * K + k0 + lk);
    As[lk + 0][lr] = a4.x; As[lk + 1][lr] = a4.y;
    As[lk + 2][lr] = a4.z; As[lk + 3][lr] = a4.w;
    float4 b4 = *reinterpret_cast<const float4*>(B + (size_t)(k0 + ty) * Nn + bn + tx * 4);
    *reinterpret_cast<float4*>(&Bs[ty][tx * 4]) = b4;
    __syncthreads();
#pragma unroll
    for (int kk = 0; kk < 16; ++kk) {
      float4 av = *reinterpret_cast<const float4*>(&As[kk][ty * 4]);
      float4 bv = *reinterpret_cast<const float4*>(&Bs[kk][tx * 4]);
      float a_[4] = {av.x, av.y, av.z, av.w};
      float b_[4] = {bv.x, bv.y, bv.z, bv.w};
#pragma unroll
      for (int ii = 0; ii < 4; ++ii)
#pragma unroll
        for (int jj = 0; jj < 4; ++jj)
          acc[ii][jj] = fmaf(a_[ii], b_[jj], acc[ii][jj]);
    }
    __syncthreads();
  }
#pragma unroll
  for (int ii = 0; ii < 4; ++ii) {
    int row = bm + ty * 4 + ii;
    if (row >= M) continue;
#pragma unroll
    for (int jj = 0; jj < 4; ++jj) {
      int col = bn + tx * 4 + jj;
      float val = acc[ii][jj];
      if (bias) val += bias[col];
      if (accum) val += C[(size_t)row * Nn + col];
      if (act) val = elu_f(val);
      C[(size_t)row * Nn + col] = val;
    }
  }
}

// ---------------- CSR build ----------------
__global__ void csr_hist(const int* __restrict__ dst, int* __restrict__ deg) {
  int e = blockIdx.x * blockDim.x + threadIdx.x;
  if (e < EE) atomicAdd(&deg[dst[e]], 1);
}

__global__ void scan1(const int* __restrict__ deg, int* __restrict__ pre,
                      int* __restrict__ bsum, int n) {
  __shared__ int s[256];
  int t = threadIdx.x;
  int i = blockIdx.x * 256 + t;
  int v = (i < n) ? deg[i] : 0;
  s[t] = v;
  __syncthreads();
  for (int off = 1; off < 256; off <<= 1) {
    int tmp = (t >= off) ? s[t - off] : 0;
    __syncthreads();
    s[t] += tmp;
    __syncthreads();
  }
  if (i < n) pre[i] = s[t] - v;
  if (t == 255) bsum[blockIdx.x] = s[255];
}

__global__ void scan2(int* __restrict__ bsum, int nb) {
  __shared__ int s[256];
  int t = threadIdx.x;
  int v = (t < nb) ? bsum[t] : 0;
  s[t] = v;
  __syncthreads();
  for (int off = 1; off < 256; off <<= 1) {
    int tmp = (t >= off) ? s[t - off] : 0;
    __syncthreads();
    s[t] += tmp;
    __syncthreads();
  }
  if (t < nb) bsum[t] = s[t] - v;
}

__global__ void scan3(const int* __restrict__ pre, const int* __restrict__ bsum,
                      const int* __restrict__ deg, int* __restrict__ row_start,
                      int* __restrict__ cursor, int n) {
  int i = blockIdx.x * 256 + threadIdx.x;
  if (i < n) {
    int v = pre[i] + bsum[blockIdx.x];
    row_start[i] = v;
    cursor[i] = v;
    if (i == n - 1) row_start[n] = v + deg[i];
  }
}

__global__ void gstart_build(const int* __restrict__ batch, int* __restrict__ gstart) {
  int n = blockIdx.x * blockDim.x + threadIdx.x;
  if (n > NN) return;
  int b = (n < NN) ? batch[n] : GG;
  int pb = (n == 0) ? -1 : batch[n - 1];
  for (int g = pb + 1; g <= b; ++g) gstart[g] = n;
}

__global__ void csr_pos(const int* __restrict__ src, const int* __restrict__ dst,
                        int* __restrict__ cursor, int* __restrict__ csr_src,
                        int* __restrict__ epos) {
  int e = blockIdx.x * blockDim.x + threadIdx.x;
  if (e >= EE) return;
  int pos = atomicAdd(&cursor[dst[e]], 1);
  csr_src[pos] = src[e];
  epos[e] = pos;
}

__global__ void out_hist(const int* __restrict__ csr_src, int* __restrict__ odeg) {
  int pos = blockIdx.x * blockDim.x + threadIdx.x;
  if (pos < EE) atomicAdd(&odeg[csr_src[pos]], 1);
}

__global__ void out_fill(const int* __restrict__ csr_src, int* __restrict__ ocursor,
                         int* __restrict__ operm) {
  int pos = blockIdx.x * blockDim.x + threadIdx.x;
  if (pos < EE) {
    int slot = atomicAdd(&ocursor[csr_src[pos]], 1);
    operm[slot] = pos;
  }
}

__global__ void sgstart_build(const int* __restrict__ out_start, const int* __restrict__ gstart,
                              int* __restrict__ sg_start) {
  int t = blockIdx.x * blockDim.x + threadIdx.x;
  if (t <= GG) sg_start[t] = out_start[gstart[t]];
}

// we0[16x64] -> split bf16 fragments, K padded to 32 (k>=16 -> 0)
__global__ void build_we0frag(const float* __restrict__ we0, u16* __restrict__ wf_hi,
                              u16* __restrict__ wf_lo) {
  int idx = blockIdx.x * 256 + threadIdx.x;  // 2048
  if (idx >= 2048) return;
  int j = idx & 7, lane = (idx >> 3) & 63, t = idx >> 9;
  int k = (lane >> 4) * 8 + j;
  int c = t * 16 + (lane & 15);
  float w = (k < 16) ? we0[(size_t)k * 64 + c] : 0.f;
  u16 hi = f2b(w);
  wf_hi[idx] = hi;
  wf_lo[idx] = f2b(w - bf2f(hi));
}

// MFMA edge encoder: ea[epos[e]] = elu(edge_attr[e] @ we0 + be0), 16 edges/wave
__global__ __launch_bounds__(256) void ea_enc_mfma(const float* __restrict__ edge_attr,
                                                   const u16* __restrict__ wf_hi,
                                                   const u16* __restrict__ wf_lo,
                                                   const float* __restrict__ be0,
                                                   const int* __restrict__ epos,
                                                   u16* __restrict__ ea) {
  int lane = threadIdx.x & 63;
  int gwave = (blockIdx.x * 256 + threadIdx.x) >> 6;
  int nwaves = (gridDim.x * 256) >> 6;
  bf16x8 bh[4], bl[4];
#pragma unroll
  for (int t = 0; t < 4; ++t) {
    bh[t] = *reinterpret_cast<const bf16x8*>(wf_hi + ((size_t)(t * 64 + lane)) * 8);
    bl[t] = *reinterpret_cast<const bf16x8*>(wf_lo + ((size_t)(t * 64 + lane)) * 8);
  }
  float bias_c[4];
#pragma unroll
  for (int t = 0; t < 4; ++t) bias_c[t] = be0[t * 16 + (lane & 15)];
  const int rif = lane & 15;
  const int kg = lane >> 4;
  for (int mt = gwave; mt < EE / 16; mt += nwaves) {
    int base = mt * 16;
    bf16x8 ah = {}, al = {};
    if (kg < 2) {
      const float* ap = edge_attr + (size_t)(base + rif) * 16 + kg * 8;
      float4 f0 = *reinterpret_cast<const float4*>(ap);
      float4 f1 = *reinterpret_cast<const float4*>(ap + 4);
      float fv[8] = {f0.x, f0.y, f0.z, f0.w, f1.x, f1.y, f1.z, f1.w};
#pragma unroll
      for (int jj = 0; jj < 8; ++jj) {
        u16 hi = f2b(fv[jj]);
        ah[jj] = (short)hi;
        al[jj] = (short)f2b(fv[jj] - bf2f(hi));
      }
    }
    f32x4 acc[4] = {};
#pragma unroll
    for (int t = 0; t < 4; ++t) {
      acc[t] = __builtin_amdgcn_mfma_f32_16x16x32_bf16(ah, bh[t], acc[t], 0, 0, 0);
      acc[t] = __builtin_amdgcn_mfma_f32_16x16x32_bf16(ah, bl[t], acc[t], 0, 0, 0);
      acc[t] = __builtin_amdgcn_mfma_f32_16x16x32_bf16(al, bh[t], acc[t], 0, 0, 0);
    }
#pragma unroll
    for (int rg = 0; rg < 4; ++rg) {
      int pr = epos[base + kg * 4 + rg];
#pragma unroll
      for (int t = 0; t < 4; ++t)
        ea[(size_t)pr * 64 + t * 16 + rif] = f2b(elu_f(acc[t][rg] + bias_c[t]));
    }
  }
}

// ---------------- graph LayerNorm ----------------
__global__ __launch_bounds__(256) void ln_stats_block(const float* __restrict__ h,
                                                      const int* __restrict__ gstart,
                                                      float* __restrict__ gmean,
                                                      float* __restrict__ grstd) {
  __shared__ float ls[4], lss[4];
  int g = blockIdx.x, t = threadIdx.x;
  int n0 = gstart[g], n1 = gstart[g + 1];
  int total4 = (n1 - n0) * 32;
  const float4* base = (const float4*)(h + (size_t)n0 * 128);
  float s = 0.f, ss = 0.f;
  for (int i = t; i < total4; i += 256) {
    float4 v = base[i];
    s += v.x + v.y + v.z + v.w;
    ss += v.x * v.x + v.y * v.y + v.z * v.z + v.w * v.w;
  }
  s = wred64(s);
  ss = wred64(ss);
  if ((t & 63) == 0) { ls[t >> 6] = s; lss[t >> 6] = ss; }
  __syncthreads();
  if (t == 0) {
    float S = ls[0] + ls[1] + ls[2] + ls[3];
    float SS = lss[0] + lss[1] + lss[2] + lss[3];
    float cnt = fmaxf((float)(n1 - n0) * 128.f, 1.0f);
    float mean = S / cnt;
    float var = fmaxf(SS / cnt - mean * mean, 0.f);
    gmean[g] = mean;
    grstd[g] = rsqrtf(var + 1e-5f);
  }
}

// LN apply -> split bf16 (hi + lo residual)
__global__ __launch_bounds__(256) void ln_apply(const float* __restrict__ in,
                                                u16* __restrict__ out_hi,
                                                u16* __restrict__ out_lo,
                                                const int* __restrict__ batch,
                                                const float* __restrict__ gmean,
                                                const float* __restrict__ grstd,
                                                const float* __restrict__ gamma,
                                                const float* __restrict__ beta) {
  int idx = blockIdx.x * blockDim.x + threadIdx.x;
  if (idx >= NN * 32) return;
  int n = idx >> 5, c4 = (idx & 31) * 4;
  int g = batch[n];
  float mean = gmean[g], rstd = grstd[g];
  float4 xv = *reinterpret_cast<const float4*>(in + (size_t)n * 128 + c4);
  float4 gv = *reinterpret_cast<const float4*>(gamma + c4);
  float4 bv = *reinterpret_cast<const float4*>(beta + c4);
  float v0 = elu_f((xv.x - mean) * rstd * gv.x + bv.x);
  float v1 = elu_f((xv.y - mean) * rstd * gv.y + bv.y);
  float v2 = elu_f((xv.z - mean) * rstd * gv.z + bv.z);
  float v3 = elu_f((xv.w - mean) * rstd * gv.w + bv.w);
  u16 h0 = f2b(v0), h1 = f2b(v1), h2 = f2b(v2), h3 = f2b(v3);
  uint2 hi = {(u32)h0 | ((u32)h1 << 16), (u32)h2 | ((u32)h3 << 16)};
  uint2 lo = {(u32)f2b(v0 - bf2f(h0)) | ((u32)f2b(v1 - bf2f(h1)) << 16),
              (u32)f2b(v2 - bf2f(h2)) | ((u32)f2b(v3 - bf2f(h3)) << 16)};
  *reinterpret_cast<uint2*>(out_hi + (size_t)n * 128 + c4) = hi;
  *reinterpret_cast<uint2*>(out_lo + (size_t)n * 128 + c4) = lo;
}

// ---------------- per-layer weight transforms ----------------
__global__ void build_wqe(const float* __restrict__ wq, const float* __restrict__ bq,
                          const float* __restrict__ we, float* __restrict__ WQE,
                          float* __restrict__ bqe) {
  int col = threadIdx.x;
  int row = blockIdx.x;
  int hh = col >> 6, j = col & 63;
  const float* wrow = (row < 128) ? (wq + (size_t)row * 128) : bq;
  float acc = 0.f;
  for (int c = 0; c < 64; ++c) acc += wrow[hh * 64 + c] * we[(size_t)j * 128 + hh * 64 + c];
  if (row < 128) WQE[(size_t)row * 128 + col] = acc;
  else bqe[col] = acc;
}

// fused: Wfrag (hi/lo) + wef (hi/lo) + ball
__global__ void build_wfrag2(const float* __restrict__ wq, const float* __restrict__ wk,
                             const float* __restrict__ wv, const float* __restrict__ WQE,
                             const float* __restrict__ wsk, const float* __restrict__ we,
                             const float* __restrict__ bq, const float* __restrict__ bk,
                             const float* __restrict__ bv, const float* __restrict__ bqe,
                             const float* __restrict__ bsk,
                             u16* __restrict__ Wfrag_hi, u16* __restrict__ Wfrag_lo,
                             u16* __restrict__ wef_hi, u16* __restrict__ wef_lo,
                             float* __restrict__ ball) {
  int idx = blockIdx.x * 256 + threadIdx.x;
  if (idx < 81920) {
    int j = idx & 7, lane = (idx >> 3) & 63, rest = idx >> 9;
    int tg = rest % 40, s = rest / 40;
    int k = s * 32 + (lane >> 4) * 8 + j;
    int col = tg * 16 + (lane & 15);
    int sel = col >> 7, c = col & 127;
    const float* src = sel == 0 ? wq : sel == 1 ? wk : sel == 2 ? wv : sel == 3 ? WQE : wsk;
    float w = src[(size_t)k * 128 + c];
    u16 hi = f2b(w);
    Wfrag_hi[idx] = hi;
    Wfrag_lo[idx] = f2b(w - bf2f(hi));
  } else if (idx < 90112) {
    int i2 = idx - 81920;
    int j = i2 & 7, lane = (i2 >> 3) & 63, rest = i2 >> 9;
    int t = rest & 3, hh = (rest >> 2) & 1, s = rest >> 3;
    int k = s * 32 + (lane >> 4) * 8 + j;
    int col = hh * 64 + t * 16 + (lane & 15);
    float w = we[(size_t)k * 128 + col];
    u16 hi = f2b(w);
    wef_hi[i2] = hi;
    wef_lo[i2] = f2b(w - bf2f(hi));
  }
  if (idx < 640) {
    int sel = idx >> 7, c = idx & 127;
    const float* s2 = sel == 0 ? bq : sel == 1 ? bk : sel == 2 ? bv : sel == 3 ? bqe : bsk;
    ball[idx] = s2[c];
  }
}

// up[64x64] f32 -> bf16 fragments
__global__ void build_upfrag(const float* __restrict__ up, u16* __restrict__ upfrag) {
  int idx = blockIdx.x * 256 + threadIdx.x;
  if (idx >= 4096) return;
  int j = idx & 7, lane = (idx >> 3) & 63, st = idx >> 9;
  int s = st >> 2, t = st & 3;
  int k = s * 32 + (lane >> 4) * 8 + j;
  int c = t * 16 + (lane & 15);
  upfrag[idx] = f2b(up[k * 64 + c]);
}

// W2 = up @ re_w; bvec = ub @ re_w; also zero gsum_in (GG*64). Launch 64 blocks.
__global__ void build_w2(const float* __restrict__ up, const float* __restrict__ ub,
                         const float* __restrict__ re_w, float* __restrict__ W2,
                         float* __restrict__ bvec, float* __restrict__ gsum_in) {
  int idx = blockIdx.x * 256 + threadIdx.x;
  if (idx < 64 * 128) {
    int k_ = idx >> 7, c = idx & 127;
    float a = 0.f;
    for (int j = 0; j < 64; ++j) a = fmaf(up[k_ * 64 + j], re_w[j * 128 + c], a);
    W2[idx] = a;
  } else if (idx < 64 * 128 + 128) {
    int c = idx - 64 * 128;
    float a = 0.f;
    for (int j = 0; j < 64; ++j) a = fmaf(ub[j], re_w[j * 128 + c], a);
    bvec[c] = a;
  }
  if (idx < GG * 64) gsum_in[idx] = 0.f;
}

// ---------------- split-precision MFMA node GEMM ----------------
// nodebuf row layout (u16 idx): q[0..127] | qe[128..255] | kv interleaved [256..511]
__global__ __launch_bounds__(256) void node_gemm(const u16* __restrict__ h_hi,
                                                 const u16* __restrict__ h_lo,
                                                 const u16* __restrict__ Wfrag_hi,
                                                 const u16* __restrict__ Wfrag_lo,
                                                 const float* __restrict__ ball,
                                                 u16* __restrict__ nodebuf,
                                                 float* __restrict__ hn) {
  int tid = threadIdx.x;
  int lane = tid & 63;
  int wv = tid >> 6;
  int cb = blockIdx.x;
  int rbase = blockIdx.y * 64 + wv * 16;
  int rif = lane & 15, kg = lane >> 4;
  f32x4 acc[4] = {};
  int arow = rbase + rif;
  bool rowok = arow < NN;
  const u16* aph = h_hi + (size_t)arow * 128 + kg * 8;
  const u16* apl = h_lo + (size_t)arow * 128 + kg * 8;
#pragma unroll
  for (int s = 0; s < 4; ++s) {
    bf16x8 ah = {}, al = {};
    if (rowok) {
      ah = *reinterpret_cast<const bf16x8*>(aph + s * 32);
      al = *reinterpret_cast<const bf16x8*>(apl + s * 32);
    }
#pragma unroll
    for (int t = 0; t < 4; ++t) {
      size_t fo = ((size_t)((s * 40 + cb * 4 + t) * 64 + lane)) * 8;
      bf16x8 bh = *reinterpret_cast<const bf16x8*>(Wfrag_hi + fo);
      bf16x8 bl = *reinterpret_cast<const bf16x8*>(Wfrag_lo + fo);
      acc[t] = __builtin_amdgcn_mfma_f32_16x16x32_bf16(ah, bh, acc[t], 0, 0, 0);
      acc[t] = __builtin_amdgcn_mfma_f32_16x16x32_bf16(ah, bl, acc[t], 0, 0, 0);
      acc[t] = __builtin_amdgcn_mfma_f32_16x16x32_bf16(al, bh, acc[t], 0, 0, 0);
    }
  }
#pragma unroll
  for (int t = 0; t < 4; ++t) {
    int col = (cb * 4 + t) * 16 + rif;
    float bia = ball[col];
#pragma unroll
    for (int rg = 0; rg < 4; ++rg) {
      int row = rbase + kg * 4 + rg;
      if (row < NN) {
        float val = acc[t][rg] + bia;
        if (col < 512) {
          int idx;
          if (col < 128) idx = col;
          else if (col < 256) { int c1 = col - 128; idx = 256 + ((c1 >> 1) << 2) + (c1 & 1); }
          else if (col < 384) { int c2 = col - 256; idx = 256 + ((c2 >> 1) << 2) + 2 + (c2 & 1); }
          else idx = 128 + (col - 384);
          nodebuf[(size_t)row * 512 + idx] = f2b(val);
        } else {
          hn[(size_t)row * 128 + col - 512] = val;
        }
      }
    }
  }
}

// ---------------- MFMA edge GEMM: ea = elu(ea @ up + ub), in place ----------------
__global__ __launch_bounds__(256) void edge_gemm(u16* __restrict__ ea,
                                                 const u16* __restrict__ upfrag,
                                                 const float* __restrict__ ub) {
  int lane = threadIdx.x & 63;
  int gwave = (blockIdx.x * 256 + threadIdx.x) >> 6;
  int nwaves = (gridDim.x * 256) >> 6;
  bf16x8 bfrag[2][4];
#pragma unroll
  for (int s = 0; s < 2; ++s)
#pragma unroll
    for (int t = 0; t < 4; ++t)
      bfrag[s][t] = *reinterpret_cast<const bf16x8*>(upfrag + ((size_t)((s * 4 + t) * 64 + lane)) * 8);
  float bias_c[4];
#pragma unroll
  for (int t = 0; t < 4; ++t) bias_c[t] = ub[t * 16 + (lane & 15)];
  const int rif = lane & 15;
  const int kg = lane >> 4;
  for (int mt = gwave; mt < EE / 16; mt += nwaves) {
    size_t rowbase = (size_t)mt * 16;
    const u16* arow = ea + (rowbase + rif) * 64;
    bf16x8 a0 = *reinterpret_cast<const bf16x8*>(arow + kg * 8);
    bf16x8 a1 = *reinterpret_cast<const bf16x8*>(arow + 32 + kg * 8);
    f32x4 acc[4] = {};
#pragma unroll
    for (int t = 0; t < 4; ++t) {
      acc[t] = __builtin_amdgcn_mfma_f32_16x16x32_bf16(a0, bfrag[0][t], acc[t], 0, 0, 0);
      acc[t] = __builtin_amdgcn_mfma_f32_16x16x32_bf16(a1, bfrag[1][t], acc[t], 0, 0, 0);
    }
#pragma unroll
    for (int t = 0; t < 4; ++t)
#pragma unroll
      for (int rg = 0; rg < 4; ++rg) {
        float val = acc[t][rg] + bias_c[t];
        ea[(rowbase + kg * 4 + rg) * 64 + t * 16 + rif] = f2b(elu_f(val));
      }
  }
}

// ---------------- split-precision MFMA BD GEMM: hn += r @ BD (per-head we) ----------------
__global__ __launch_bounds__(256) void bd_gemm(const u16* __restrict__ r_hi,
                                               const u16* __restrict__ r_lo,
                                               const u16* __restrict__ wef_hi,
                                               const u16* __restrict__ wef_lo,
                                               float* __restrict__ hn) {
  int tid = threadIdx.x;
  int lane = tid & 63;
  int w = blockIdx.x * 4 + (tid >> 6);
  if (w >= NN / 16) return;
  int rif = lane & 15, kg = lane >> 4;
  size_t rowbase = (size_t)w * 16;
  const u16* ahb = r_hi + (rowbase + rif) * 128;
  const u16* alb = r_lo + (rowbase + rif) * 128;
  f32x4 acc[2][4] = {};
#pragma unroll
  for (int hh = 0; hh < 2; ++hh)
#pragma unroll
    for (int s = 0; s < 2; ++s) {
      int ko = hh * 64 + s * 32 + kg * 8;
      bf16x8 ah = *reinterpret_cast<const bf16x8*>(ahb + ko);
      bf16x8 al = *reinterpret_cast<const bf16x8*>(alb + ko);
#pragma unroll
      for (int t = 0; t < 4; ++t) {
        size_t fo = ((size_t)((((s * 2 + hh) * 4 + t)) * 64 + lane)) * 8;
        bf16x8 bh = *reinterpret_cast<const bf16x8*>(wef_hi + fo);
        bf16x8 bl = *reinterpret_cast<const bf16x8*>(wef_lo + fo);
        acc[hh][t] = __builtin_amdgcn_mfma_f32_16x16x32_bf16(ah, bh, acc[hh][t], 0, 0, 0);
        acc[hh][t] = __builtin_amdgcn_mfma_f32_16x16x32_bf16(ah, bl, acc[hh][t], 0, 0, 0);
        acc[hh][t] = __builtin_amdgcn_mfma_f32_16x16x32_bf16(al, bh, acc[hh][t], 0, 0, 0);
      }
    }
#pragma unroll
  for (int hh = 0; hh < 2; ++hh)
#pragma unroll
    for (int t = 0; t < 4; ++t)
#pragma unroll
      for (int rg = 0; rg < 4; ++rg) {
        size_t row = rowbase + kg * 4 + rg;
        int col = hh * 64 + t * 16 + rif;
        hn[row * 128 + col] += acc[hh][t][rg];
      }
}

// per-src-graph sum of current ea rows, chunked + atomic merge
__global__ __launch_bounds__(256) void gsum_pre(const u16* __restrict__ ea,
                                                const int* __restrict__ sg_start,
                                                const int* __restrict__ sg_perm,
                                                float* __restrict__ gsum_in) {
  __shared__ float red[8][64];
  int g = blockIdx.x, t = threadIdx.x;
  int c2 = t & 31;
  int rgrp = t >> 5;
  int gr = blockIdx.y * 8 + rgrp;
  int p0 = sg_start[g], p1 = sg_start[g + 1];
  float slo = 0.f, shi = 0.f;
  for (int i = p0 + gr; i < p1; i += 128) {
    int pos = sg_perm[i];
    u32 w = ((const u32*)ea)[(size_t)pos * 32 + c2];
    slo += lo2f(w);
    shi += hi2f(w);
  }
  red[rgrp][c2 * 2] = slo;
  red[rgrp][c2 * 2 + 1] = shi;
  __syncthreads();
  if (t < 64) {
    float a = 0.f;
#pragma unroll
    for (int rr = 0; rr < 8; ++rr) a += red[rr][t];
    atomicAdd(&gsum_in[(size_t)g * 64 + t], a);
  }
}

// embE = elu(gsum_in @ W2 + cnt*bvec + re_b)
__global__ void emb_e_kernel(const float* __restrict__ gsum_in, const int* __restrict__ sg_start,
                             const float* __restrict__ W2, const float* __restrict__ bvec,
                             const float* __restrict__ re_b, float* __restrict__ embE) {
  int g = blockIdx.x, c = threadIdx.x;
  float cnt = (float)(sg_start[g + 1] - sg_start[g]);
  float a = re_b[c] + cnt * bvec[c];
  for (int k_ = 0; k_ < 64; ++k_) a = fmaf(gsum_in[(size_t)g * 64 + k_], W2[k_ * 128 + c], a);
  embE[(size_t)g * 128 + c] = elu_f(a);
}

// ---------------- fused flash attention: one wave per dst, 4 edges/wave ----------------
// 16 lanes per edge (group = lane>>4); lane owns 8 channels (li*8..+8).
// li<8 -> head0 state, li>=8 -> head1 state. Per-head reduce = 3 shfl over 8 lanes.
__global__ __launch_bounds__(256) void attn_node(const u32* __restrict__ nb32,
                                                 const u32* __restrict__ ea32,
                                                 const int* __restrict__ row_start,
                                                 const int* __restrict__ csr_src,
                                                 float* __restrict__ hn,
                                                 u32* __restrict__ r_hi,
                                                 u32* __restrict__ r_lo) {
  int d = (blockIdx.x * blockDim.x + threadIdx.x) >> 6;
  if (d >= NN) return;
  int lane = threadIdx.x & 63;
  int grp = lane >> 4;
  int li = lane & 15;
  int qi = li * 4;                                  // u32 pair base (0..60)
  int eai = (li & 7) * 4;                           // ea u32 base
  int ridx = ((li >> 3) << 5) + ((li & 7) << 2);    // r u32 idx
  int p0 = row_start[d], p1 = row_start[d + 1];
  if (p0 == p1) {
    if (grp == 0) {
      uint4 z = {0u, 0u, 0u, 0u};
      *reinterpret_cast<uint4*>(r_hi + (size_t)d * 64 + ridx) = z;
      *reinterpret_cast<uint4*>(r_lo + (size_t)d * 64 + ridx) = z;
    }
    return;
  }
  size_t dbase = (size_t)d * 256;
  uint4 qp = *reinterpret_cast<const uint4*>(nb32 + dbase + qi);
  uint4 qep = *reinterpret_cast<const uint4*>(nb32 + dbase + 64 + qi);
  float q_[8] = {lo2f(qp.x), hi2f(qp.x), lo2f(qp.y), hi2f(qp.y),
                 lo2f(qp.z), hi2f(qp.z), lo2f(qp.w), hi2f(qp.w)};
  float g_[8] = {lo2f(qep.x), hi2f(qep.x), lo2f(qep.y), hi2f(qep.y),
                 lo2f(qep.z), hi2f(qep.z), lo2f(qep.w), hi2f(qep.w)};
  int cnt = p1 - p0;
  float m = -3.4e38f, ss = 0.f;
  float a_[8] = {}, r_[8] = {};
  int i = grp;
  bool vld = i < cnt;
  int pc = vld ? p0 + i : p0;
  int sc = csr_src[pc];
  const u32* kp = nb32 + (size_t)sc * 256 + 128 + qi * 2;
  uint4 kva = *reinterpret_cast<const uint4*>(kp);
  uint4 kvb = *reinterpret_cast<const uint4*>(kp + 4);
  uint4 ev = *reinterpret_cast<const uint4*>(ea32 + (size_t)pc * 32 + eai);
  int nIter = (cnt + 3) >> 2;
  for (int j = 0; j < nIter; ++j) {
    int i2 = i + 4;
    bool nvld = i2 < cnt;
    int pn = nvld ? p0 + i2 : p0;
    int sn = csr_src[pn];
    const u32* kpn = nb32 + (size_t)sn * 256 + 128 + qi * 2;
    uint4 kvan = *reinterpret_cast<const uint4*>(kpn);
    uint4 kvbn = *reinterpret_cast<const uint4*>(kpn + 4);
    uint4 evn = *reinterpret_cast<const uint4*>(ea32 + (size_t)pn * 32 + eai);
    float e_[8] = {lo2f(ev.x), hi2f(ev.x), lo2f(ev.y), hi2f(ev.y),
                   lo2f(ev.z), hi2f(ev.z), lo2f(ev.w), hi2f(ev.w)};
    float kk[8] = {lo2f(kva.x), hi2f(kva.x), lo2f(kva.z), hi2f(kva.z),
                   lo2f(kvb.x), hi2f(kvb.x), lo2f(kvb.z), hi2f(kvb.z)};
    float vv[8] = {lo2f(kva.y), hi2f(kva.y), lo2f(kva.w), hi2f(kva.w),
                   lo2f(kvb.y), hi2f(kvb.y), lo2f(kvb.w), hi2f(kvb.w)};
    float p = 0.f;
#pragma unroll
    for (int t = 0; t < 8; ++t) p = fmaf(q_[t], kk[t], fmaf(g_[t], e_[t], p));
#pragma unroll
    for (int mm = 1; mm <= 4; mm <<= 1) p += __shfl_xor(p, mm, 64);  // 8-lane head sum
    float lg = vld ? p * 0.125f : -3.4e38f;
    float mn = fmaxf(m, lg);
    float f = __expf(m - mn), w = __expf(lg - mn);
    ss = ss * f + w;
#pragma unroll
    for (int t = 0; t < 8; ++t) {
      a_[t] = fmaf(w, vv[t], a_[t] * f);
      r_[t] = fmaf(w, e_[t], r_[t] * f);
    }
    m = mn;
    i = i2; vld = nvld; kva = kvan; kvb = kvbn; ev = evn;
  }
  // merge the 4 edge groups (xor 16, then xor 32)
#pragma unroll
  for (int mk = 16; mk <= 32; mk <<= 1) {
    float mo = __shfl_xor(m, mk, 64);
    float so = __shfl_xor(ss, mk, 64);
    float ao[8], ro[8];
#pragma unroll
    for (int t = 0; t < 8; ++t) {
      ao[t] = __shfl_xor(a_[t], mk, 64);
      ro[t] = __shfl_xor(r_[t], mk, 64);
    }
    float mn = fmaxf(m, mo);
    float fs = __expf(m - mn), fo = __expf(mo - mn);
    ss = ss * fs + so * fo;
#pragma unroll
    for (int t = 0; t < 8; ++t) {
      a_[t] = a_[t] * fs + ao[t] * fo;
      r_[t] = r_[t] * fs + ro[t] * fo;
    }
    m = mn;
  }
  if (grp == 0) {
    float inv = 1.f / ss;
    float* hp = hn + (size_t)d * 128 + li * 8;
    float4 h0 = *reinterpret_cast<float4*>(hp);
    float4 h1 = *reinterpret_cast<float4*>(hp + 4);
    h0.x += a_[0] * inv; h0.y += a_[1] * inv; h0.z += a_[2] * inv; h0.w += a_[3] * inv;
    h1.x += a_[4] * inv; h1.y += a_[5] * inv; h1.z += a_[6] * inv; h1.w += a_[7] * inv;
    *reinterpret_cast<float4*>(hp) = h0;
    *reinterpret_cast<float4*>(hp + 4) = h1;
    float rv[8];
    u16 rh16[8];
#pragma unroll
    for (int t = 0; t < 8; ++t) { rv[t] = r_[t] * inv; rh16[t] = f2b(rv[t]); }
    uint4 rh = {(u32)rh16[0] | ((u32)rh16[1] << 16), (u32)rh16[2] | ((u32)rh16[3] << 16),
                (u32)rh16[4] | ((u32)rh16[5] << 16), (u32)rh16[6] | ((u32)rh16[7] << 16)};
    uint4 rl;
    u32 rl16[8];
#pragma unroll
    for (int t = 0; t < 8; ++t) rl16[t] = (u32)f2b(rv[t] - bf2f(rh16[t]));
    rl.x = rl16[0] | (rl16[1] << 16); rl.y = rl16[2] | (rl16[3] << 16);
    rl.z = rl16[4] | (rl16[5] << 16); rl.w = rl16[6] | (rl16[7] << 16);
    *reinterpret_cast<uint4*>(r_hi + (size_t)d * 64 + ridx) = rh;
    *reinterpret_cast<uint4*>(r_lo + (size_t)d * 64 + ridx) = rl;
  }
}

// ---------------- SAG pooling ----------------
__global__ __launch_bounds__(256) void node_dots(const float* __restrict__ hn,
                                                 const float* __restrict__ wrel,
                                                 const float* __restrict__ wroot,
                                                 float* __restrict__ hrel,
                                                 float* __restrict__ troot,
                                                 unsigned* __restrict__ gm,
                                                 float* __restrict__ gs) {
  int tid0 = blockIdx.x * blockDim.x + threadIdx.x;
  if (tid0 < GG) gm[tid0] = 0u;
  else if (tid0 < 2 * GG) gs[tid0 - GG] = 0.f;
  int n = tid0 >> 6;
  if (n >= NN) return;
  int lane = threadIdx.x & 63;
  float x0 = hn[(size_t)n * 128 + lane], x1 = hn[(size_t)n * 128 + 64 + lane];
  float tr = wred64(x0 * wrel[lane] + x1 * wrel[64 + lane]);
  float tt = wred64(x0 * wroot[lane] + x1 * wroot[64 + lane]);
  if (lane == 0) { hrel[n] = tr; troot[n] = tt; }
}

__global__ __launch_bounds__(256) void sag_gather(const float* __restrict__ hrel,
                                                  const float* __restrict__ troot,
                                                  const float* __restrict__ brel,
                                                  const int* __restrict__ row_start,
                                                  const int* __restrict__ csr_src,
                                                  const int* __restrict__ batch,
                                                  float* __restrict__ sc, unsigned* __restrict__ gm) {
  int n = blockIdx.x * blockDim.x + threadIdx.x;
  if (n >= NN) return;
  float s = 0.f;
  int p1 = row_start[n + 1];
  for (int pos = row_start[n]; pos < p1; ++pos) s += hrel[csr_src[pos]];
  float v = s + troot[n] + brel[0];
  sc[n] = v;
  atomicMax(&gm[batch[n]], fenc(v));
}

__global__ __launch_bounds__(256) void sag_exp(const float* __restrict__ sc,
                                               const int* __restrict__ batch,
                                               const unsigned* __restrict__ gm,
                                               float* __restrict__ gs, float* __restrict__ scp) {
  int n = blockIdx.x * blockDim.x + threadIdx.x;
  if (n >= NN) return;
  int g = batch[n];
  float p = __expf(sc[n] - fdec(gm[g]));
  scp[n] = p;
  atomicAdd(&gs[g], p);
}

__global__ void emb_block(const float* __restrict__ hn, const float* __restrict__ scp,
                          const float* __restrict__ gs, const int* __restrict__ gstart,
                          const float* __restrict__ embE, float* __restrict__ dstv) {
  __shared__ float part[2];
  int g = blockIdx.x, c = threadIdx.x;
  int n0 = gstart[g], n1 = gstart[g + 1];
  float invg = 1.f / gs[g];
  float acc = 0.f;
  for (int n = n0; n < n1; ++n) acc = fmaf(hn[(size_t)n * 128 + c], scp[n] * invg, acc);
  float val = acc * embE[(size_t)g * 128 + c];
  float sq = val * val;
#pragma unroll
  for (int mm = 32; mm; mm >>= 1) sq += __shfl_xor(sq, mm, 64);
  if ((c & 63) == 0) part[c >> 6] = sq;
  __syncthreads();
  float nrm = sqrtf(part[0] + part[1]);
  dstv[(size_t)g * 128 + c] = elu_f(val / fmaxf(nrm, 1e-12f));
}

__global__ void final_combine(const float* __restrict__ e0, const float* __restrict__ e1,
                              float* __restrict__ out) {
  int idx = blockIdx.x * blockDim.x + threadIdx.x;
  if (idx >= GG * 128) return;
  out[idx] = 0.6f * e0[idx] + 0.4f * e1[idx];
}

// =====================================================================
extern "C" void kernel_launch(void* const* d_in, const int* in_sizes, int n_in,
                              void* d_out, int out_size, void* d_ws, size_t ws_size,
                              hipStream_t stream) {
  const float* x = (const float*)d_in[0];
  const float* edge_attr = (const float*)d_in[1];
  const int* edge_index = (const int*)d_in[2];
  const int* batch = (const int*)d_in[3];
  const float* w0 = (const float*)d_in[4];
  const float* b0 = (const float*)d_in[5];
  const float* we0 = (const float*)d_in[6];
  const float* be0 = (const float*)d_in[7];
  const float* ln0_g = (const float*)d_in[8];
  const float* ln0_b = (const float*)d_in[9];
  const float* qkv_w = (const float*)d_in[10];
  const float* qkv_b = (const float*)d_in[11];
  const float* edge_w = (const float*)d_in[12];
  const float* skip_w = (const float*)d_in[13];
  const float* skip_b = (const float*)d_in[14];
  const float* up_w = (const float*)d_in[15];
  const float* up_b = (const float*)d_in[16];
  const float* ng = (const float*)d_in[17];
  const float* nbeta = (const float*)d_in[18];
  const float* sag_wrel = (const float*)d_in[19];
  const float* sag_brel = (const float*)d_in[20];
  const float* sag_wroot = (const float*)d_in[21];
  const float* re_w = (const float*)d_in[22];
  const float* re_b = (const float*)d_in[23];
  const int* srcp = edge_index;
  const int* dstp = edge_index + EE;
  float* out = (float*)d_out;
  (void)in_sizes; (void)n_in;

  float* ws = (float*)d_ws;
  size_t o = 0;
  auto alloc = [&](size_t n) { n = (n + 3) & ~(size_t)3; float* p = ws + o; o += n; return p; };
  u16* h_hi = (u16*)alloc((size_t)NN * 64);
  u16* h_lo = (u16*)alloc((size_t)NN * 64);
  float* hn = alloc((size_t)NN * 128);
  u32* r_hi = (u32*)alloc((size_t)NN * 64);
  u32* r_lo = (u32*)alloc((size_t)NN * 64);
  u16* nodebuf = (u16*)alloc((size_t)NN * 256);   // NN x 512 bf16 (q|qe|kv)
  u16* ea = (u16*)alloc((size_t)EE * 32);         // EE x 64 bf16, dst-CSR order
  int* csr_src = (int*)alloc(EE);
  int* epos = (int*)alloc(EE);
  int* deg = (int*)alloc(NN);
  int* pre = (int*)alloc(NN);
  int* bsum = (int*)alloc(256);
  int* row_start = (int*)alloc(NN + 1);
  int* cursor = (int*)alloc(NN);
  int* out_start = (int*)alloc(NN + 1);
  int* gstart = (int*)alloc(GG + 1);
  int* sg_perm = (int*)alloc(EE);
  int* sg_start = (int*)alloc(GG + 1);
  float* gsum_in = alloc(GG * 64);
  float* W2 = alloc(64 * 128);
  float* bvec = alloc(128);
  u16* upfrag = (u16*)alloc(2048);
  u16* Wfrag_hi = (u16*)alloc(40960);
  u16* Wfrag_lo = (u16*)alloc(40960);
  u16* wef_hi = (u16*)alloc(4096);
  u16* wef_lo = (u16*)alloc(4096);
  u16* wef0_hi = (u16*)alloc(1024);
  u16* wef0_lo = (u16*)alloc(1024);
  unsigned* gm = (unsigned*)alloc(GG);
  float* gs = alloc(GG);
  float* gmean = alloc(GG);
  float* grstd = alloc(GG);
  float* WQE = alloc(128 * 128);
  float* bqe = alloc(128);
  float* ball = alloc(640);
  float* hrel = alloc(NN);
  float* troot = alloc(NN);
  float* sc = alloc(NN);
  float* scp = alloc(NN);
  float* embE = alloc(GG * 128);
  float* embs0 = alloc(GG * 128);
  float* embs1 = alloc(GG * 128);

  const size_t need = o * sizeof(float);
  if (ws_size < need) {
    hipMemsetAsync(d_out, 0, (size_t)out_size * sizeof(float), stream);
    return;
  }
  const int NSCAN = (NN + 255) / 256;  // 196

  auto gemm = [&](const float* A, const float* B, const float* bias, float* C,
                  int M, int Nn, int K, int act, int accum) {
    dim3 g((Nn + 63) / 64, (M + 63) / 64);
    gemm_kernel<<<g, 256, 0, stream>>>(A, B, bias, C, M, Nn, K, act, accum);
  };
  auto ex_scan = [&](const int* degp, int* startp, int* curp) {
    scan1<<<NSCAN, 256, 0, stream>>>(degp, pre, bsum, NN);
    scan2<<<1, 256, 0, stream>>>(bsum, NSCAN);
    scan3<<<NSCAN, 256, 0, stream>>>(pre, bsum, degp, startp, curp, NN);
  };
  auto graph_ln = [&](const float* in, const float* gamma, const float* beta) {
    ln_stats_block<<<GG, 256, 0, stream>>>(in, gstart, gmean, grstd);
    ln_apply<<<NN * 32 / 256, 256, 0, stream>>>(in, h_hi, h_lo, batch, gmean, grstd, gamma, beta);
  };
  auto tconv = [&](int il) {
    const float* wq = qkv_w + (size_t)(il * 3 + 0) * 128 * 128;
    const float* wk = qkv_w + (size_t)(il * 3 + 1) * 128 * 128;
    const float* wv = qkv_w + (size_t)(il * 3 + 2) * 128 * 128;
    const float* bq = qkv_b + (il * 3 + 0) * 128;
    const float* bk = qkv_b + (il * 3 + 1) * 128;
    const float* bv = qkv_b + (il * 3 + 2) * 128;
    const float* we = edge_w + (size_t)il * 64 * 128;
    const float* wsk = skip_w + (size_t)il * 128 * 128;
    const float* bsk = skip_b + il * 128;
    build_wqe<<<129, 128, 0, stream>>>(wq, bq, we, WQE, bqe);
    build_wfrag2<<<352, 256, 0, stream>>>(wq, wk, wv, WQE, wsk, we, bq, bk, bv, bqe, bsk,
                                          Wfrag_hi, Wfrag_lo, wef_hi, wef_lo, ball);
    dim3 ng2(10, (NN + 63) / 64);
    node_gemm<<<ng2, 256, 0, stream>>>(h_hi, h_lo, Wfrag_hi, Wfrag_lo, ball, nodebuf, hn);
    attn_node<<<NN / 4, 256, 0, stream>>>((const u32*)nodebuf, (const u32*)ea, row_start,
                                          csr_src, hn, r_hi, r_lo);
    bd_gemm<<<(NN / 16 + 3) / 4, 256, 0, stream>>>((const u16*)r_hi, (const u16*)r_lo,
                                                   wef_hi, wef_lo, hn);
  };
  auto ea_mlp = [&](int il) {
    build_upfrag<<<16, 256, 0, stream>>>(up_w + (size_t)il * 4096, upfrag);
    edge_gemm<<<2048, 256, 0, stream>>>(ea, upfrag, up_b + il * 64);
  };

  // one-time topology structures
  hipMemsetAsync(deg, 0, NN * sizeof(int), stream);
  csr_hist<<<(EE + 255) / 256, 256, 0, stream>>>(dstp, deg);
  ex_scan(deg, row_start, cursor);
  gstart_build<<<(NN + 256) / 256, 256, 0, stream>>>(batch, gstart);
  csr_pos<<<(EE + 255) / 256, 256, 0, stream>>>(srcp, dstp, cursor, csr_src, epos);
  build_we0frag<<<8, 256, 0, stream>>>(we0, wef0_hi, wef0_lo);
  ea_enc_mfma<<<2048, 256, 0, stream>>>(edge_attr, wef0_hi, wef0_lo, be0, epos, ea);
  hipMemsetAsync(deg, 0, NN * sizeof(int), stream);
  out_hist<<<(EE + 255) / 256, 256, 0, stream>>>(csr_src, deg);
  ex_scan(deg, out_start, cursor);
  out_fill<<<(EE + 255) / 256, 256, 0, stream>>>(csr_src, cursor, sg_perm);
  sgstart_build<<<2, 256, 0, stream>>>(out_start, gstart, sg_start);
  // node encoder + first LN
  gemm(x, w0, b0, hn, NN, 128, 64, 0, 0);
  graph_ln(hn, ln0_g, ln0_b);

  for (int i = 0; i < 2; ++i) {
    tconv(i * 2 + 0);
    graph_ln(hn, ng + (i * 2) * 128, nbeta + (i * 2) * 128);
    ea_mlp(i * 2);
    tconv(i * 2 + 1);
    // SAG pooling on pre-LN conv2 output hn; edge emb via linearity
    build_w2<<<64, 256, 0, stream>>>(up_w + (size_t)(i * 2 + 1) * 4096,
                                     up_b + (i * 2 + 1) * 64,
                                     re_w + (size_t)i * 64 * 128, W2, bvec, gsum_in);
    dim3 gsg(GG, 16);
    gsum_pre<<<gsg, 256, 0, stream>>>(ea, sg_start, sg_perm, gsum_in);
    if (i == 0) ea_mlp(i * 2 + 1);  // ea after last SAG is never consumed
    node_dots<<<NN / 4, 256, 0, stream>>>(hn, sag_wrel + i * 128, sag_wroot + i * 128,
                                          hrel, troot, gm, gs);
    sag_gather<<<(NN + 255) / 256, 256, 0, stream>>>(hrel, troot, sag_brel + i, row_start,
                                                     csr_src, batch, sc, gm);
    sag_exp<<<(NN + 255) / 256, 256, 0, stream>>>(sc, batch, gm, gs, scp);
    emb_e_kernel<<<GG, 128, 0, stream>>>(gsum_in, sg_start, W2, bvec, re_b + i * 128, embE);
    emb_block<<<GG, 128, 0, stream>>>(hn, scp, gs, gstart, embE, i == 0 ? embs0 : embs1);
    if (i == 0) graph_ln(hn, ng + (i * 2 + 1) * 128, nbeta + (i * 2 + 1) * 128);
  }
  final_combine<<<GG * 128 / 256, 256, 0, stream>>>(embs0, embs1, out);
}

// Round 13
// 1695.364 us; speedup vs baseline: 1.2317x; 1.0335x over previous
//
#include <hip/hip_runtime.h>
#include <math.h>

#define NN 50000
#define EE 800000
#define GG 256

typedef unsigned short u16;
typedef unsigned int u32;
typedef __attribute__((ext_vector_type(4))) float f32x4;
typedef __attribute__((ext_vector_type(8))) short bf16x8;

__device__ __forceinline__ float elu_f(float x) { return x > 0.f ? x : expm1f(x); }

__device__ __forceinline__ unsigned fenc(float f) {
  unsigned b = __float_as_uint(f);
  return (b & 0x80000000u) ? ~b : (b | 0x80000000u);
}
__device__ __forceinline__ float fdec(unsigned u) {
  return __uint_as_float((u & 0x80000000u) ? (u ^ 0x80000000u) : ~u);
}
__device__ __forceinline__ u16 f2b(float f) {
  u32 u = __float_as_uint(f);
  u32 r = (u + 0x7fffu + ((u >> 16) & 1u)) >> 16;
  return (u16)r;
}
__device__ __forceinline__ float bf2f(u16 u) { return __uint_as_float(((u32)u) << 16); }
__device__ __forceinline__ float lo2f(u32 p) { return __uint_as_float(p << 16); }
__device__ __forceinline__ float hi2f(u32 p) { return __uint_as_float(p & 0xffff0000u); }

__device__ __forceinline__ float wred64(float v) {
#pragma unroll
  for (int m = 32; m; m >>= 1) v += __shfl_xor(v, m, 64);
  return v;
}

// ---------------- generic tiled f32 GEMM: C = act(A@B + bias (+C)) ----------------
__global__ __launch_bounds__(256) void gemm_kernel(
    const float* __restrict__ A, const float* __restrict__ B,
    const float* __restrict__ bias, float* __restrict__ C,
    int M, int Nn, int K, int act, int accum) {
  __shared__ float As[16][68];
  __shared__ float Bs[16][68];
  const int bm = blockIdx.y * 64;
  const int bn = blockIdx.x * 64;
  const int tid = threadIdx.x;
  const int tx = tid & 15, ty = tid >> 4;
  const int lr = tid >> 2;
  const int lk = (tid & 3) << 2;
  float acc[4][4] = {};
  for (int k0 = 0; k0 < K; k0 += 16) {
    int arow = bm + lr;
    float4 a4 = {0.f, 0.f, 0.f, 0.f};
    if (arow < M) a4 = *reinterpret_cast<const float4*>(A + (size_t)arow * K + k0 + lk);
    As[lk + 0][lr] = a4.x; As[lk + 1][lr] = a4.y;
    As[lk + 2][lr] = a4.z; As[lk + 3][lr] = a4.w;
    float4 b4 = *reinterpret_cast<const float4*>(B + (size_t)(k0 + ty) * Nn + bn + tx * 4);
    *reinterpret_cast<float4*>(&Bs[ty][tx * 4]) = b4;
    __syncthreads();
#pragma unroll
    for (int kk = 0; kk < 16; ++kk) {
      float4 av = *reinterpret_cast<const float4*>(&As[kk][ty * 4]);
      float4 bv = *reinterpret_cast<const float4*>(&Bs[kk][tx * 4]);
      float a_[4] = {av.x, av.y, av.z, av.w};
      float b_[4] = {bv.x, bv.y, bv.z, bv.w};
#pragma unroll
      for (int ii = 0; ii < 4; ++ii)
#pragma unroll
        for (int jj = 0; jj < 4; ++jj)
          acc[ii][jj] = fmaf(a_[ii], b_[jj], acc[ii][jj]);
    }
    __syncthreads();
  }
#pragma unroll
  for (int ii = 0; ii < 4; ++ii) {
    int row = bm + ty * 4 + ii;
    if (row >= M) continue;
#pragma unroll
    for (int jj = 0; jj < 4; ++jj) {
      int col = bn + tx * 4 + jj;
      float val = acc[ii][jj];
      if (bias) val += bias[col];
      if (accum) val += C[(size_t)row * Nn + col];
      if (act) val = elu_f(val);
      C[(size_t)row * Nn + col] = val;
    }
  }
}

// ---------------- CSR build ----------------
__global__ void csr_hist(const int* __restrict__ dst, int* __restrict__ deg) {
  int e = blockIdx.x * blockDim.x + threadIdx.x;
  if (e < EE) atomicAdd(&deg[dst[e]], 1);
}

__global__ void scan1(const int* __restrict__ deg, int* __restrict__ pre,
                      int* __restrict__ bsum, int n) {
  __shared__ int s[256];
  int t = threadIdx.x;
  int i = blockIdx.x * 256 + t;
  int v = (i < n) ? deg[i] : 0;
  s[t] = v;
  __syncthreads();
  for (int off = 1; off < 256; off <<= 1) {
    int tmp = (t >= off) ? s[t - off] : 0;
    __syncthreads();
    s[t] += tmp;
    __syncthreads();
  }
  if (i < n) pre[i] = s[t] - v;
  if (t == 255) bsum[blockIdx.x] = s[255];
}

__global__ void scan2(int* __restrict__ bsum, int nb) {
  __shared__ int s[256];
  int t = threadIdx.x;
  int v = (t < nb) ? bsum[t] : 0;
  s[t] = v;
  __syncthreads();
  for (int off = 1; off < 256; off <<= 1) {
    int tmp = (t >= off) ? s[t - off] : 0;
    __syncthreads();
    s[t] += tmp;
    __syncthreads();
  }
  if (t < nb) bsum[t] = s[t] - v;
}

__global__ void scan3(const int* __restrict__ pre, const int* __restrict__ bsum,
                      const int* __restrict__ deg, int* __restrict__ row_start,
                      int* __restrict__ cursor, int n) {
  int i = blockIdx.x * 256 + threadIdx.x;
  if (i < n) {
    int v = pre[i] + bsum[blockIdx.x];
    row_start[i] = v;
    cursor[i] = v;
    if (i == n - 1) row_start[n] = v + deg[i];
  }
}

__global__ void gstart_build(const int* __restrict__ batch, int* __restrict__ gstart) {
  int n = blockIdx.x * blockDim.x + threadIdx.x;
  if (n > NN) return;
  int b = (n < NN) ? batch[n] : GG;
  int pb = (n == 0) ? -1 : batch[n - 1];
  for (int g = pb + 1; g <= b; ++g) gstart[g] = n;
}

__global__ void csr_pos(const int* __restrict__ src, const int* __restrict__ dst,
                        int* __restrict__ cursor, int* __restrict__ csr_src,
                        int* __restrict__ epos) {
  int e = blockIdx.x * blockDim.x + threadIdx.x;
  if (e >= EE) return;
  int pos = atomicAdd(&cursor[dst[e]], 1);
  csr_src[pos] = src[e];
  epos[e] = pos;
}

__global__ void out_hist(const int* __restrict__ csr_src, int* __restrict__ odeg) {
  int pos = blockIdx.x * blockDim.x + threadIdx.x;
  if (pos < EE) atomicAdd(&odeg[csr_src[pos]], 1);
}

__global__ void out_fill(const int* __restrict__ csr_src, int* __restrict__ ocursor,
                         int* __restrict__ operm) {
  int pos = blockIdx.x * blockDim.x + threadIdx.x;
  if (pos < EE) {
    int slot = atomicAdd(&ocursor[csr_src[pos]], 1);
    operm[slot] = pos;
  }
}

__global__ void sgstart_build(const int* __restrict__ out_start, const int* __restrict__ gstart,
                              int* __restrict__ sg_start) {
  int t = blockIdx.x * blockDim.x + threadIdx.x;
  if (t <= GG) sg_start[t] = out_start[gstart[t]];
}

// we0[16x64] -> split bf16 fragments, K padded to 32 (k>=16 -> 0)
__global__ void build_we0frag(const float* __restrict__ we0, u16* __restrict__ wf_hi,
                              u16* __restrict__ wf_lo) {
  int idx = blockIdx.x * 256 + threadIdx.x;  // 2048
  if (idx >= 2048) return;
  int j = idx & 7, lane = (idx >> 3) & 63, t = idx >> 9;
  int k = (lane >> 4) * 8 + j;
  int c = t * 16 + (lane & 15);
  float w = (k < 16) ? we0[(size_t)k * 64 + c] : 0.f;
  u16 hi = f2b(w);
  wf_hi[idx] = hi;
  wf_lo[idx] = f2b(w - bf2f(hi));
}

// MFMA edge encoder: ea[epos[e]] = elu(edge_attr[e] @ we0 + be0), 16 edges/wave
__global__ __launch_bounds__(256) void ea_enc_mfma(const float* __restrict__ edge_attr,
                                                   const u16* __restrict__ wf_hi,
                                                   const u16* __restrict__ wf_lo,
                                                   const float* __restrict__ be0,
                                                   const int* __restrict__ epos,
                                                   u16* __restrict__ ea) {
  int lane = threadIdx.x & 63;
  int gwave = (blockIdx.x * 256 + threadIdx.x) >> 6;
  int nwaves = (gridDim.x * 256) >> 6;
  bf16x8 bh[4], bl[4];
#pragma unroll
  for (int t = 0; t < 4; ++t) {
    bh[t] = *reinterpret_cast<const bf16x8*>(wf_hi + ((size_t)(t * 64 + lane)) * 8);
    bl[t] = *reinterpret_cast<const bf16x8*>(wf_lo + ((size_t)(t * 64 + lane)) * 8);
  }
  float bias_c[4];
#pragma unroll
  for (int t = 0; t < 4; ++t) bias_c[t] = be0[t * 16 + (lane & 15)];
  const int rif = lane & 15;
  const int kg = lane >> 4;
  for (int mt = gwave; mt < EE / 16; mt += nwaves) {
    int base = mt * 16;
    bf16x8 ah = {}, al = {};
    if (kg < 2) {
      const float* ap = edge_attr + (size_t)(base + rif) * 16 + kg * 8;
      float4 f0 = *reinterpret_cast<const float4*>(ap);
      float4 f1 = *reinterpret_cast<const float4*>(ap + 4);
      float fv[8] = {f0.x, f0.y, f0.z, f0.w, f1.x, f1.y, f1.z, f1.w};
#pragma unroll
      for (int jj = 0; jj < 8; ++jj) {
        u16 hi = f2b(fv[jj]);
        ah[jj] = (short)hi;
        al[jj] = (short)f2b(fv[jj] - bf2f(hi));
      }
    }
    f32x4 acc[4] = {};
#pragma unroll
    for (int t = 0; t < 4; ++t) {
      acc[t] = __builtin_amdgcn_mfma_f32_16x16x32_bf16(ah, bh[t], acc[t], 0, 0, 0);
      acc[t] = __builtin_amdgcn_mfma_f32_16x16x32_bf16(ah, bl[t], acc[t], 0, 0, 0);
      acc[t] = __builtin_amdgcn_mfma_f32_16x16x32_bf16(al, bh[t], acc[t], 0, 0, 0);
    }
#pragma unroll
    for (int rg = 0; rg < 4; ++rg) {
      int pr = epos[base + kg * 4 + rg];
#pragma unroll
      for (int t = 0; t < 4; ++t)
        ea[(size_t)pr * 64 + t * 16 + rif] = f2b(elu_f(acc[t][rg] + bias_c[t]));
    }
  }
}

// ---------------- graph LayerNorm ----------------
__global__ __launch_bounds__(256) void ln_stats_block(const float* __restrict__ h,
                                                      const int* __restrict__ gstart,
                                                      float* __restrict__ gmean,
                                                      float* __restrict__ grstd) {
  __shared__ float ls[4], lss[4];
  int g = blockIdx.x, t = threadIdx.x;
  int n0 = gstart[g], n1 = gstart[g + 1];
  int total4 = (n1 - n0) * 32;
  const float4* base = (const float4*)(h + (size_t)n0 * 128);
  float s = 0.f, ss = 0.f;
  for (int i = t; i < total4; i += 256) {
    float4 v = base[i];
    s += v.x + v.y + v.z + v.w;
    ss += v.x * v.x + v.y * v.y + v.z * v.z + v.w * v.w;
  }
  s = wred64(s);
  ss = wred64(ss);
  if ((t & 63) == 0) { ls[t >> 6] = s; lss[t >> 6] = ss; }
  __syncthreads();
  if (t == 0) {
    float S = ls[0] + ls[1] + ls[2] + ls[3];
    float SS = lss[0] + lss[1] + lss[2] + lss[3];
    float cnt = fmaxf((float)(n1 - n0) * 128.f, 1.0f);
    float mean = S / cnt;
    float var = fmaxf(SS / cnt - mean * mean, 0.f);
    gmean[g] = mean;
    grstd[g] = rsqrtf(var + 1e-5f);
  }
}

// LN apply -> split bf16 (hi + lo residual)
__global__ __launch_bounds__(256) void ln_apply(const float* __restrict__ in,
                                                u16* __restrict__ out_hi,
                                                u16* __restrict__ out_lo,
                                                const int* __restrict__ batch,
                                                const float* __restrict__ gmean,
                                                const float* __restrict__ grstd,
                                                const float* __restrict__ gamma,
                                                const float* __restrict__ beta) {
  int idx = blockIdx.x * blockDim.x + threadIdx.x;
  if (idx >= NN * 32) return;
  int n = idx >> 5, c4 = (idx & 31) * 4;
  int g = batch[n];
  float mean = gmean[g], rstd = grstd[g];
  float4 xv = *reinterpret_cast<const float4*>(in + (size_t)n * 128 + c4);
  float4 gv = *reinterpret_cast<const float4*>(gamma + c4);
  float4 bv = *reinterpret_cast<const float4*>(beta + c4);
  float v0 = elu_f((xv.x - mean) * rstd * gv.x + bv.x);
  float v1 = elu_f((xv.y - mean) * rstd * gv.y + bv.y);
  float v2 = elu_f((xv.z - mean) * rstd * gv.z + bv.z);
  float v3 = elu_f((xv.w - mean) * rstd * gv.w + bv.w);
  u16 h0 = f2b(v0), h1 = f2b(v1), h2 = f2b(v2), h3 = f2b(v3);
  uint2 hi = {(u32)h0 | ((u32)h1 << 16), (u32)h2 | ((u32)h3 << 16)};
  uint2 lo = {(u32)f2b(v0 - bf2f(h0)) | ((u32)f2b(v1 - bf2f(h1)) << 16),
              (u32)f2b(v2 - bf2f(h2)) | ((u32)f2b(v3 - bf2f(h3)) << 16)};
  *reinterpret_cast<uint2*>(out_hi + (size_t)n * 128 + c4) = hi;
  *reinterpret_cast<uint2*>(out_lo + (size_t)n * 128 + c4) = lo;
}

// ---------------- per-layer weight transforms ----------------
__global__ void build_wqe(const float* __restrict__ wq, const float* __restrict__ bq,
                          const float* __restrict__ we, float* __restrict__ WQE,
                          float* __restrict__ bqe) {
  int col = threadIdx.x;
  int row = blockIdx.x;
  int hh = col >> 6, j = col & 63;
  const float* wrow = (row < 128) ? (wq + (size_t)row * 128) : bq;
  float acc = 0.f;
  for (int c = 0; c < 64; ++c) acc += wrow[hh * 64 + c] * we[(size_t)j * 128 + hh * 64 + c];
  if (row < 128) WQE[(size_t)row * 128 + col] = acc;
  else bqe[col] = acc;
}

// fused: Wfrag (hi/lo) + wef (hi/lo) + ball
__global__ void build_wfrag2(const float* __restrict__ wq, const float* __restrict__ wk,
                             const float* __restrict__ wv, const float* __restrict__ WQE,
                             const float* __restrict__ wsk, const float* __restrict__ we,
                             const float* __restrict__ bq, const float* __restrict__ bk,
                             const float* __restrict__ bv, const float* __restrict__ bqe,
                             const float* __restrict__ bsk,
                             u16* __restrict__ Wfrag_hi, u16* __restrict__ Wfrag_lo,
                             u16* __restrict__ wef_hi, u16* __restrict__ wef_lo,
                             float* __restrict__ ball) {
  int idx = blockIdx.x * 256 + threadIdx.x;
  if (idx < 81920) {
    int j = idx & 7, lane = (idx >> 3) & 63, rest = idx >> 9;
    int tg = rest % 40, s = rest / 40;
    int k = s * 32 + (lane >> 4) * 8 + j;
    int col = tg * 16 + (lane & 15);
    int sel = col >> 7, c = col & 127;
    const float* src = sel == 0 ? wq : sel == 1 ? wk : sel == 2 ? wv : sel == 3 ? WQE : wsk;
    float w = src[(size_t)k * 128 + c];
    u16 hi = f2b(w);
    Wfrag_hi[idx] = hi;
    Wfrag_lo[idx] = f2b(w - bf2f(hi));
  } else if (idx < 90112) {
    int i2 = idx - 81920;
    int j = i2 & 7, lane = (i2 >> 3) & 63, rest = i2 >> 9;
    int t = rest & 3, hh = (rest >> 2) & 1, s = rest >> 3;
    int k = s * 32 + (lane >> 4) * 8 + j;
    int col = hh * 64 + t * 16 + (lane & 15);
    float w = we[(size_t)k * 128 + col];
    u16 hi = f2b(w);
    wef_hi[i2] = hi;
    wef_lo[i2] = f2b(w - bf2f(hi));
  }
  if (idx < 640) {
    int sel = idx >> 7, c = idx & 127;
    const float* s2 = sel == 0 ? bq : sel == 1 ? bk : sel == 2 ? bv : sel == 3 ? bqe : bsk;
    ball[idx] = s2[c];
  }
}

// up[64x64] f32 -> bf16 fragments
__global__ void build_upfrag(const float* __restrict__ up, u16* __restrict__ upfrag) {
  int idx = blockIdx.x * 256 + threadIdx.x;
  if (idx >= 4096) return;
  int j = idx & 7, lane = (idx >> 3) & 63, st = idx >> 9;
  int s = st >> 2, t = st & 3;
  int k = s * 32 + (lane >> 4) * 8 + j;
  int c = t * 16 + (lane & 15);
  upfrag[idx] = f2b(up[k * 64 + c]);
}

// W2 = up @ re_w; bvec = ub @ re_w; also zero gsum_in (GG*64). Launch 64 blocks.
__global__ void build_w2(const float* __restrict__ up, const float* __restrict__ ub,
                         const float* __restrict__ re_w, float* __restrict__ W2,
                         float* __restrict__ bvec, float* __restrict__ gsum_in) {
  int idx = blockIdx.x * 256 + threadIdx.x;
  if (idx < 64 * 128) {
    int k_ = idx >> 7, c = idx & 127;
    float a = 0.f;
    for (int j = 0; j < 64; ++j) a = fmaf(up[k_ * 64 + j], re_w[j * 128 + c], a);
    W2[idx] = a;
  } else if (idx < 64 * 128 + 128) {
    int c = idx - 64 * 128;
    float a = 0.f;
    for (int j = 0; j < 64; ++j) a = fmaf(ub[j], re_w[j * 128 + c], a);
    bvec[c] = a;
  }
  if (idx < GG * 64) gsum_in[idx] = 0.f;
}

// ---------------- split-precision MFMA node GEMM ----------------
// nodebuf row layout (u16 idx): q[0..127] | qe[128..255] | k[256..383] | v[384..511]
// One block = 64 rows; loop over the 10 column-blocks so A is read once.
__global__ __launch_bounds__(256) void node_gemm(const u16* __restrict__ h_hi,
                                                 const u16* __restrict__ h_lo,
                                                 const u16* __restrict__ Wfrag_hi,
                                                 const u16* __restrict__ Wfrag_lo,
                                                 const float* __restrict__ ball,
                                                 u16* __restrict__ nodebuf,
                                                 float* __restrict__ hn) {
  int tid = threadIdx.x;
  int lane = tid & 63;
  int wv = tid >> 6;
  int rbase = blockIdx.x * 64 + wv * 16;
  int rif = lane & 15, kg = lane >> 4;
  int arow = rbase + rif;
  bool rowok = arow < NN;
  const u16* aph = h_hi + (size_t)arow * 128 + kg * 8;
  const u16* apl = h_lo + (size_t)arow * 128 + kg * 8;
  bf16x8 ah[4], al[4];
#pragma unroll
  for (int s = 0; s < 4; ++s) {
    ah[s] = bf16x8{};
    al[s] = bf16x8{};
    if (rowok) {
      ah[s] = *reinterpret_cast<const bf16x8*>(aph + s * 32);
      al[s] = *reinterpret_cast<const bf16x8*>(apl + s * 32);
    }
  }
  for (int cb = 0; cb < 10; ++cb) {
    f32x4 acc[4] = {};
#pragma unroll
    for (int s = 0; s < 4; ++s) {
#pragma unroll
      for (int t = 0; t < 4; ++t) {
        size_t fo = ((size_t)((s * 40 + cb * 4 + t) * 64 + lane)) * 8;
        bf16x8 bh = *reinterpret_cast<const bf16x8*>(Wfrag_hi + fo);
        bf16x8 bl = *reinterpret_cast<const bf16x8*>(Wfrag_lo + fo);
        acc[t] = __builtin_amdgcn_mfma_f32_16x16x32_bf16(ah[s], bh, acc[t], 0, 0, 0);
        acc[t] = __builtin_amdgcn_mfma_f32_16x16x32_bf16(ah[s], bl, acc[t], 0, 0, 0);
        acc[t] = __builtin_amdgcn_mfma_f32_16x16x32_bf16(al[s], bh, acc[t], 0, 0, 0);
      }
    }
#pragma unroll
    for (int t = 0; t < 4; ++t) {
      int col = (cb * 4 + t) * 16 + rif;
      float bia = ball[col];
#pragma unroll
      for (int rg = 0; rg < 4; ++rg) {
        int row = rbase + kg * 4 + rg;
        if (row < NN) {
          float val = acc[t][rg] + bia;
          if (col < 512) {
            // q: col<128 -> col; k: 128..255 -> col+128; v: 256..383 -> col+128; qe: 384..511 -> col-256
            int idx = (col < 128) ? col : (col < 384 ? col + 128 : col - 256);
            nodebuf[(size_t)row * 512 + idx] = f2b(val);
          } else {
            hn[(size_t)row * 128 + col - 512] = val;
          }
        }
      }
    }
  }
}

// ---------------- MFMA edge GEMM: ea = elu(ea @ up + ub), in place ----------------
__global__ __launch_bounds__(256) void edge_gemm(u16* __restrict__ ea,
                                                 const u16* __restrict__ upfrag,
                                                 const float* __restrict__ ub) {
  int lane = threadIdx.x & 63;
  int gwave = (blockIdx.x * 256 + threadIdx.x) >> 6;
  int nwaves = (gridDim.x * 256) >> 6;
  bf16x8 bfrag[2][4];
#pragma unroll
  for (int s = 0; s < 2; ++s)
#pragma unroll
    for (int t = 0; t < 4; ++t)
      bfrag[s][t] = *reinterpret_cast<const bf16x8*>(upfrag + ((size_t)((s * 4 + t) * 64 + lane)) * 8);
  float bias_c[4];
#pragma unroll
  for (int t = 0; t < 4; ++t) bias_c[t] = ub[t * 16 + (lane & 15)];
  const int rif = lane & 15;
  const int kg = lane >> 4;
  for (int mt = gwave; mt < EE / 16; mt += nwaves) {
    size_t rowbase = (size_t)mt * 16;
    const u16* arow = ea + (rowbase + rif) * 64;
    bf16x8 a0 = *reinterpret_cast<const bf16x8*>(arow + kg * 8);
    bf16x8 a1 = *reinterpret_cast<const bf16x8*>(arow + 32 + kg * 8);
    f32x4 acc[4] = {};
#pragma unroll
    for (int t = 0; t < 4; ++t) {
      acc[t] = __builtin_amdgcn_mfma_f32_16x16x32_bf16(a0, bfrag[0][t], acc[t], 0, 0, 0);
      acc[t] = __builtin_amdgcn_mfma_f32_16x16x32_bf16(a1, bfrag[1][t], acc[t], 0, 0, 0);
    }
#pragma unroll
    for (int t = 0; t < 4; ++t)
#pragma unroll
      for (int rg = 0; rg < 4; ++rg) {
        float val = acc[t][rg] + bias_c[t];
        ea[(rowbase + kg * 4 + rg) * 64 + t * 16 + rif] = f2b(elu_f(val));
      }
  }
}

// ---------------- split-precision MFMA BD GEMM: hn += r @ BD (per-head we) ----------------
__global__ __launch_bounds__(256) void bd_gemm(const u16* __restrict__ r_hi,
                                               const u16* __restrict__ r_lo,
                                               const u16* __restrict__ wef_hi,
                                               const u16* __restrict__ wef_lo,
                                               float* __restrict__ hn) {
  int tid = threadIdx.x;
  int lane = tid & 63;
  int w = blockIdx.x * 4 + (tid >> 6);
  if (w >= NN / 16) return;
  int rif = lane & 15, kg = lane >> 4;
  size_t rowbase = (size_t)w * 16;
  const u16* ahb = r_hi + (rowbase + rif) * 128;
  const u16* alb = r_lo + (rowbase + rif) * 128;
  f32x4 acc[2][4] = {};
#pragma unroll
  for (int hh = 0; hh < 2; ++hh)
#pragma unroll
    for (int s = 0; s < 2; ++s) {
      int ko = hh * 64 + s * 32 + kg * 8;
      bf16x8 ah = *reinterpret_cast<const bf16x8*>(ahb + ko);
      bf16x8 al = *reinterpret_cast<const bf16x8*>(alb + ko);
#pragma unroll
      for (int t = 0; t < 4; ++t) {
        size_t fo = ((size_t)((((s * 2 + hh) * 4 + t)) * 64 + lane)) * 8;
        bf16x8 bh = *reinterpret_cast<const bf16x8*>(wef_hi + fo);
        bf16x8 bl = *reinterpret_cast<const bf16x8*>(wef_lo + fo);
        acc[hh][t] = __builtin_amdgcn_mfma_f32_16x16x32_bf16(ah, bh, acc[hh][t], 0, 0, 0);
        acc[hh][t] = __builtin_amdgcn_mfma_f32_16x16x32_bf16(ah, bl, acc[hh][t], 0, 0, 0);
        acc[hh][t] = __builtin_amdgcn_mfma_f32_16x16x32_bf16(al, bh, acc[hh][t], 0, 0, 0);
      }
    }
#pragma unroll
  for (int hh = 0; hh < 2; ++hh)
#pragma unroll
    for (int t = 0; t < 4; ++t)
#pragma unroll
      for (int rg = 0; rg < 4; ++rg) {
        size_t row = rowbase + kg * 4 + rg;
        int col = hh * 64 + t * 16 + rif;
        hn[row * 128 + col] += acc[hh][t][rg];
      }
}

// per-src-graph sum of current ea rows, chunked + atomic merge
__global__ __launch_bounds__(256) void gsum_pre(const u16* __restrict__ ea,
                                                const int* __restrict__ sg_start,
                                                const int* __restrict__ sg_perm,
                                                float* __restrict__ gsum_in) {
  __shared__ float red[8][64];
  int g = blockIdx.x, t = threadIdx.x;
  int c2 = t & 31;
  int rgrp = t >> 5;
  int gr = blockIdx.y * 8 + rgrp;
  int p0 = sg_start[g], p1 = sg_start[g + 1];
  float slo = 0.f, shi = 0.f;
  for (int i = p0 + gr; i < p1; i += 128) {
    int pos = sg_perm[i];
    u32 w = ((const u32*)ea)[(size_t)pos * 32 + c2];
    slo += lo2f(w);
    shi += hi2f(w);
  }
  red[rgrp][c2 * 2] = slo;
  red[rgrp][c2 * 2 + 1] = shi;
  __syncthreads();
  if (t < 64) {
    float a = 0.f;
#pragma unroll
    for (int rr = 0; rr < 8; ++rr) a += red[rr][t];
    atomicAdd(&gsum_in[(size_t)g * 64 + t], a);
  }
}

// embE = elu(gsum_in @ W2 + cnt*bvec + re_b)
__global__ void emb_e_kernel(const float* __restrict__ gsum_in, const int* __restrict__ sg_start,
                             const float* __restrict__ W2, const float* __restrict__ bvec,
                             const float* __restrict__ re_b, float* __restrict__ embE) {
  int g = blockIdx.x, c = threadIdx.x;
  float cnt = (float)(sg_start[g + 1] - sg_start[g]);
  float a = re_b[c] + cnt * bvec[c];
  for (int k_ = 0; k_ < 64; ++k_) a = fmaf(gsum_in[(size_t)g * 64 + k_], W2[k_ * 128 + c], a);
  embE[(size_t)g * 128 + c] = elu_f(a);
}

// ---------------- fused flash attention: one wave per dst, 4 edges/wave ----------------
// 16 lanes per edge (group = lane>>4); lane owns 8 channels (li*8..+8).
__global__ __launch_bounds__(256) void attn_node(const u32* __restrict__ nb32,
                                                 const u32* __restrict__ ea32,
                                                 const int* __restrict__ row_start,
                                                 const int* __restrict__ csr_src,
                                                 float* __restrict__ hn,
                                                 u32* __restrict__ r_hi,
                                                 u32* __restrict__ r_lo) {
  int d = (blockIdx.x * blockDim.x + threadIdx.x) >> 6;
  if (d >= NN) return;
  int lane = threadIdx.x & 63;
  int grp = lane >> 4;
  int li = lane & 15;
  int qi = li * 4;                                  // u32 base within region
  int eai = (li & 7) * 4;                           // ea u32 base
  int ridx = ((li >> 3) << 5) + ((li & 7) << 2);    // r u32 idx
  int p0 = row_start[d], p1 = row_start[d + 1];
  if (p0 == p1) {
    if (grp == 0) {
      uint4 z = {0u, 0u, 0u, 0u};
      *reinterpret_cast<uint4*>(r_hi + (size_t)d * 64 + ridx) = z;
      *reinterpret_cast<uint4*>(r_lo + (size_t)d * 64 + ridx) = z;
    }
    return;
  }
  size_t dbase = (size_t)d * 256;
  uint4 qp = *reinterpret_cast<const uint4*>(nb32 + dbase + qi);
  uint4 qep = *reinterpret_cast<const uint4*>(nb32 + dbase + 64 + qi);
  float q_[8] = {lo2f(qp.x), hi2f(qp.x), lo2f(qp.y), hi2f(qp.y),
                 lo2f(qp.z), hi2f(qp.z), lo2f(qp.w), hi2f(qp.w)};
  float g_[8] = {lo2f(qep.x), hi2f(qep.x), lo2f(qep.y), hi2f(qep.y),
                 lo2f(qep.z), hi2f(qep.z), lo2f(qep.w), hi2f(qep.w)};
  int cnt = p1 - p0;
  float m = -3.4e38f, ss = 0.f;
  float a_[8] = {}, r_[8] = {};
  int i = grp;
  bool vld = i < cnt;
  int pc = vld ? p0 + i : p0;
  int sc = csr_src[pc];
  const u32* kp = nb32 + (size_t)sc * 256 + 128 + qi;
  uint4 kvk = *reinterpret_cast<const uint4*>(kp);        // k
  uint4 kvv = *reinterpret_cast<const uint4*>(kp + 64);   // v
  uint4 ev = *reinterpret_cast<const uint4*>(ea32 + (size_t)pc * 32 + eai);
  int nIter = (cnt + 3) >> 2;
  for (int j = 0; j < nIter; ++j) {
    int i2 = i + 4;
    bool nvld = i2 < cnt;
    int pn = nvld ? p0 + i2 : p0;
    int sn = csr_src[pn];
    const u32* kpn = nb32 + (size_t)sn * 256 + 128 + qi;
    uint4 kvkn = *reinterpret_cast<const uint4*>(kpn);
    uint4 kvvn = *reinterpret_cast<const uint4*>(kpn + 64);
    uint4 evn = *reinterpret_cast<const uint4*>(ea32 + (size_t)pn * 32 + eai);
    float e_[8] = {lo2f(ev.x), hi2f(ev.x), lo2f(ev.y), hi2f(ev.y),
                   lo2f(ev.z), hi2f(ev.z), lo2f(ev.w), hi2f(ev.w)};
    float kk[8] = {lo2f(kvk.x), hi2f(kvk.x), lo2f(kvk.y), hi2f(kvk.y),
                   lo2f(kvk.z), hi2f(kvk.z), lo2f(kvk.w), hi2f(kvk.w)};
    float vv[8] = {lo2f(kvv.x), hi2f(kvv.x), lo2f(kvv.y), hi2f(kvv.y),
                   lo2f(kvv.z), hi2f(kvv.z), lo2f(kvv.w), hi2f(kvv.w)};
    float p = 0.f;
#pragma unroll
    for (int t = 0; t < 8; ++t) p = fmaf(q_[t], kk[t], fmaf(g_[t], e_[t], p));
#pragma unroll
    for (int mm = 1; mm <= 4; mm <<= 1) p += __shfl_xor(p, mm, 64);  // 8-lane head sum
    float lg = vld ? p * 0.125f : -3.4e38f;
    float mn = fmaxf(m, lg);
    float f = __expf(m - mn), w = __expf(lg - mn);
    ss = ss * f + w;
#pragma unroll
    for (int t = 0; t < 8; ++t) {
      a_[t] = fmaf(w, vv[t], a_[t] * f);
      r_[t] = fmaf(w, e_[t], r_[t] * f);
    }
    m = mn;
    i = i2; vld = nvld; kvk = kvkn; kvv = kvvn; ev = evn;
  }
  // merge the 4 edge groups (xor 16, then xor 32)
#pragma unroll
  for (int mk = 16; mk <= 32; mk <<= 1) {
    float mo = __shfl_xor(m, mk, 64);
    float so = __shfl_xor(ss, mk, 64);
    float ao[8], ro[8];
#pragma unroll
    for (int t = 0; t < 8; ++t) {
      ao[t] = __shfl_xor(a_[t], mk, 64);
      ro[t] = __shfl_xor(r_[t], mk, 64);
    }
    float mn = fmaxf(m, mo);
    float fs = __expf(m - mn), fo = __expf(mo - mn);
    ss = ss * fs + so * fo;
#pragma unroll
    for (int t = 0; t < 8; ++t) {
      a_[t] = a_[t] * fs + ao[t] * fo;
      r_[t] = r_[t] * fs + ro[t] * fo;
    }
    m = mn;
  }
  if (grp == 0) {
    float inv = 1.f / ss;
    float* hp = hn + (size_t)d * 128 + li * 8;
    float4 h0 = *reinterpret_cast<float4*>(hp);
    float4 h1 = *reinterpret_cast<float4*>(hp + 4);
    h0.x += a_[0] * inv; h0.y += a_[1] * inv; h0.z += a_[2] * inv; h0.w += a_[3] * inv;
    h1.x += a_[4] * inv; h1.y += a_[5] * inv; h1.z += a_[6] * inv; h1.w += a_[7] * inv;
    *reinterpret_cast<float4*>(hp) = h0;
    *reinterpret_cast<float4*>(hp + 4) = h1;
    float rv[8];
    u16 rh16[8];
#pragma unroll
    for (int t = 0; t < 8; ++t) { rv[t] = r_[t] * inv; rh16[t] = f2b(rv[t]); }
    uint4 rh = {(u32)rh16[0] | ((u32)rh16[1] << 16), (u32)rh16[2] | ((u32)rh16[3] << 16),
                (u32)rh16[4] | ((u32)rh16[5] << 16), (u32)rh16[6] | ((u32)rh16[7] << 16)};
    uint4 rl;
    u32 rl16[8];
#pragma unroll
    for (int t = 0; t < 8; ++t) rl16[t] = (u32)f2b(rv[t] - bf2f(rh16[t]));
    rl.x = rl16[0] | (rl16[1] << 16); rl.y = rl16[2] | (rl16[3] << 16);
    rl.z = rl16[4] | (rl16[5] << 16); rl.w = rl16[6] | (rl16[7] << 16);
    *reinterpret_cast<uint4*>(r_hi + (size_t)d * 64 + ridx) = rh;
    *reinterpret_cast<uint4*>(r_lo + (size_t)d * 64 + ridx) = rl;
  }
}

// ---------------- SAG pooling ----------------
__global__ __launch_bounds__(256) void node_dots(const float* __restrict__ hn,
                                                 const float* __restrict__ wrel,
                                                 const float* __restrict__ wroot,
                                                 float* __restrict__ hrel,
                                                 float* __restrict__ troot,
                                                 unsigned* __restrict__ gm,
                                                 float* __restrict__ gs) {
  int tid0 = blockIdx.x * blockDim.x + threadIdx.x;
  if (tid0 < GG) gm[tid0] = 0u;
  else if (tid0 < 2 * GG) gs[tid0 - GG] = 0.f;
  int n = tid0 >> 6;
  if (n >= NN) return;
  int lane = threadIdx.x & 63;
  float x0 = hn[(size_t)n * 128 + lane], x1 = hn[(size_t)n * 128 + 64 + lane];
  float tr = wred64(x0 * wrel[lane] + x1 * wrel[64 + lane]);
  float tt = wred64(x0 * wroot[lane] + x1 * wroot[64 + lane]);
  if (lane == 0) { hrel[n] = tr; troot[n] = tt; }
}

__global__ __launch_bounds__(256) void sag_gather(const float* __restrict__ hrel,
                                                  const float* __restrict__ troot,
                                                  const float* __restrict__ brel,
                                                  const int* __restrict__ row_start,
                                                  const int* __restrict__ csr_src,
                                                  const int* __restrict__ batch,
                                                  float* __restrict__ sc, unsigned* __restrict__ gm) {
  int n = blockIdx.x * blockDim.x + threadIdx.x;
  if (n >= NN) return;
  float s = 0.f;
  int p1 = row_start[n + 1];
  for (int pos = row_start[n]; pos < p1; ++pos) s += hrel[csr_src[pos]];
  float v = s + troot[n] + brel[0];
  sc[n] = v;
  atomicMax(&gm[batch[n]], fenc(v));
}

__global__ __launch_bounds__(256) void sag_exp(const float* __restrict__ sc,
                                               const int* __restrict__ batch,
                                               const unsigned* __restrict__ gm,
                                               float* __restrict__ gs, float* __restrict__ scp) {
  int n = blockIdx.x * blockDim.x + threadIdx.x;
  if (n >= NN) return;
  int g = batch[n];
  float p = __expf(sc[n] - fdec(gm[g]));
  scp[n] = p;
  atomicAdd(&gs[g], p);
}

__global__ void emb_block(const float* __restrict__ hn, const float* __restrict__ scp,
                          const float* __restrict__ gs, const int* __restrict__ gstart,
                          const float* __restrict__ embE, float* __restrict__ dstv) {
  __shared__ float part[2];
  int g = blockIdx.x, c = threadIdx.x;
  int n0 = gstart[g], n1 = gstart[g + 1];
  float invg = 1.f / gs[g];
  float acc = 0.f;
  for (int n = n0; n < n1; ++n) acc = fmaf(hn[(size_t)n * 128 + c], scp[n] * invg, acc);
  float val = acc * embE[(size_t)g * 128 + c];
  float sq = val * val;
#pragma unroll
  for (int mm = 32; mm; mm >>= 1) sq += __shfl_xor(sq, mm, 64);
  if ((c & 63) == 0) part[c >> 6] = sq;
  __syncthreads();
  float nrm = sqrtf(part[0] + part[1]);
  dstv[(size_t)g * 128 + c] = elu_f(val / fmaxf(nrm, 1e-12f));
}

__global__ void final_combine(const float* __restrict__ e0, const float* __restrict__ e1,
                              float* __restrict__ out) {
  int idx = blockIdx.x * blockDim.x + threadIdx.x;
  if (idx >= GG * 128) return;
  out[idx] = 0.6f * e0[idx] + 0.4f * e1[idx];
}

// =====================================================================
extern "C" void kernel_launch(void* const* d_in, const int* in_sizes, int n_in,
                              void* d_out, int out_size, void* d_ws, size_t ws_size,
                              hipStream_t stream) {
  const float* x = (const float*)d_in[0];
  const float* edge_attr = (const float*)d_in[1];
  const int* edge_index = (const int*)d_in[2];
  const int* batch = (const int*)d_in[3];
  const float* w0 = (const float*)d_in[4];
  const float* b0 = (const float*)d_in[5];
  const float* we0 = (const float*)d_in[6];
  const float* be0 = (const float*)d_in[7];
  const float* ln0_g = (const float*)d_in[8];
  const float* ln0_b = (const float*)d_in[9];
  const float* qkv_w = (const float*)d_in[10];
  const float* qkv_b = (const float*)d_in[11];
  const float* edge_w = (const float*)d_in[12];
  const float* skip_w = (const float*)d_in[13];
  const float* skip_b = (const float*)d_in[14];
  const float* up_w = (const float*)d_in[15];
  const float* up_b = (const float*)d_in[16];
  const float* ng = (const float*)d_in[17];
  const float* nbeta = (const float*)d_in[18];
  const float* sag_wrel = (const float*)d_in[19];
  const float* sag_brel = (const float*)d_in[20];
  const float* sag_wroot = (const float*)d_in[21];
  const float* re_w = (const float*)d_in[22];
  const float* re_b = (const float*)d_in[23];
  const int* srcp = edge_index;
  const int* dstp = edge_index + EE;
  float* out = (float*)d_out;
  (void)in_sizes; (void)n_in;

  float* ws = (float*)d_ws;
  size_t o = 0;
  auto alloc = [&](size_t n) { n = (n + 3) & ~(size_t)3; float* p = ws + o; o += n; return p; };
  u16* h_hi = (u16*)alloc((size_t)NN * 64);
  u16* h_lo = (u16*)alloc((size_t)NN * 64);
  float* hn = alloc((size_t)NN * 128);
  u32* r_hi = (u32*)alloc((size_t)NN * 64);
  u32* r_lo = (u32*)alloc((size_t)NN * 64);
  u16* nodebuf = (u16*)alloc((size_t)NN * 256);   // NN x 512 bf16 (q|qe|k|v)
  u16* ea = (u16*)alloc((size_t)EE * 32);         // EE x 64 bf16, dst-CSR order
  int* csr_src = (int*)alloc(EE);
  int* epos = (int*)alloc(EE);
  int* deg = (int*)alloc(NN);
  int* pre = (int*)alloc(NN);
  int* bsum = (int*)alloc(256);
  int* row_start = (int*)alloc(NN + 1);
  int* cursor = (int*)alloc(NN);
  int* out_start = (int*)alloc(NN + 1);
  int* gstart = (int*)alloc(GG + 1);
  int* sg_perm = (int*)alloc(EE);
  int* sg_start = (int*)alloc(GG + 1);
  float* gsum_in = alloc(GG * 64);
  float* W2 = alloc(64 * 128);
  float* bvec = alloc(128);
  u16* upfrag = (u16*)alloc(2048);
  u16* Wfrag_hi = (u16*)alloc(40960);
  u16* Wfrag_lo = (u16*)alloc(40960);
  u16* wef_hi = (u16*)alloc(4096);
  u16* wef_lo = (u16*)alloc(4096);
  u16* wef0_hi = (u16*)alloc(1024);
  u16* wef0_lo = (u16*)alloc(1024);
  unsigned* gm = (unsigned*)alloc(GG);
  float* gs = alloc(GG);
  float* gmean = alloc(GG);
  float* grstd = alloc(GG);
  float* WQE = alloc(128 * 128);
  float* bqe = alloc(128);
  float* ball = alloc(640);
  float* hrel = alloc(NN);
  float* troot = alloc(NN);
  float* sc = alloc(NN);
  float* scp = alloc(NN);
  float* embE = alloc(GG * 128);
  float* embs0 = alloc(GG * 128);
  float* embs1 = alloc(GG * 128);

  const size_t need = o * sizeof(float);
  if (ws_size < need) {
    hipMemsetAsync(d_out, 0, (size_t)out_size * sizeof(float), stream);
    return;
  }
  const int NSCAN = (NN + 255) / 256;  // 196

  auto gemm = [&](const float* A, const float* B, const float* bias, float* C,
                  int M, int Nn, int K, int act, int accum) {
    dim3 g((Nn + 63) / 64, (M + 63) / 64);
    gemm_kernel<<<g, 256, 0, stream>>>(A, B, bias, C, M, Nn, K, act, accum);
  };
  auto ex_scan = [&](const int* degp, int* startp, int* curp) {
    scan1<<<NSCAN, 256, 0, stream>>>(degp, pre, bsum, NN);
    scan2<<<1, 256, 0, stream>>>(bsum, NSCAN);
    scan3<<<NSCAN, 256, 0, stream>>>(pre, bsum, degp, startp, curp, NN);
  };
  auto graph_ln = [&](const float* in, const float* gamma, const float* beta) {
    ln_stats_block<<<GG, 256, 0, stream>>>(in, gstart, gmean, grstd);
    ln_apply<<<NN * 32 / 256, 256, 0, stream>>>(in, h_hi, h_lo, batch, gmean, grstd, gamma, beta);
  };
  auto tconv = [&](int il) {
    const float* wq = qkv_w + (size_t)(il * 3 + 0) * 128 * 128;
    const float* wk = qkv_w + (size_t)(il * 3 + 1) * 128 * 128;
    const float* wv = qkv_w + (size_t)(il * 3 + 2) * 128 * 128;
    const float* bq = qkv_b + (il * 3 + 0) * 128;
    const float* bk = qkv_b + (il * 3 + 1) * 128;
    const float* bv = qkv_b + (il * 3 + 2) * 128;
    const float* we = edge_w + (size_t)il * 64 * 128;
    const float* wsk = skip_w + (size_t)il * 128 * 128;
    const float* bsk = skip_b + il * 128;
    build_wqe<<<129, 128, 0, stream>>>(wq, bq, we, WQE, bqe);
    build_wfrag2<<<352, 256, 0, stream>>>(wq, wk, wv, WQE, wsk, we, bq, bk, bv, bqe, bsk,
                                          Wfrag_hi, Wfrag_lo, wef_hi, wef_lo, ball);
    node_gemm<<<(NN + 63) / 64, 256, 0, stream>>>(h_hi, h_lo, Wfrag_hi, Wfrag_lo, ball,
                                                  nodebuf, hn);
    attn_node<<<NN / 4, 256, 0, stream>>>((const u32*)nodebuf, (const u32*)ea, row_start,
                                          csr_src, hn, r_hi, r_lo);
    bd_gemm<<<(NN / 16 + 3) / 4, 256, 0, stream>>>((const u16*)r_hi, (const u16*)r_lo,
                                                   wef_hi, wef_lo, hn);
  };
  auto ea_mlp = [&](int il) {
    build_upfrag<<<16, 256, 0, stream>>>(up_w + (size_t)il * 4096, upfrag);
    edge_gemm<<<2048, 256, 0, stream>>>(ea, upfrag, up_b + il * 64);
  };

  // one-time topology structures
  hipMemsetAsync(deg, 0, NN * sizeof(int), stream);
  csr_hist<<<(EE + 255) / 256, 256, 0, stream>>>(dstp, deg);
  ex_scan(deg, row_start, cursor);
  gstart_build<<<(NN + 256) / 256, 256, 0, stream>>>(batch, gstart);
  csr_pos<<<(EE + 255) / 256, 256, 0, stream>>>(srcp, dstp, cursor, csr_src, epos);
  build_we0frag<<<8, 256, 0, stream>>>(we0, wef0_hi, wef0_lo);
  ea_enc_mfma<<<2048, 256, 0, stream>>>(edge_attr, wef0_hi, wef0_lo, be0, epos, ea);
  hipMemsetAsync(deg, 0, NN * sizeof(int), stream);
  out_hist<<<(EE + 255) / 256, 256, 0, stream>>>(csr_src, deg);
  ex_scan(deg, out_start, cursor);
  out_fill<<<(EE + 255) / 256, 256, 0, stream>>>(csr_src, cursor, sg_perm);
  sgstart_build<<<2, 256, 0, stream>>>(out_start, gstart, sg_start);
  // node encoder + first LN
  gemm(x, w0, b0, hn, NN, 128, 64, 0, 0);
  graph_ln(hn, ln0_g, ln0_b);

  for (int i = 0; i < 2; ++i) {
    tconv(i * 2 + 0);
    graph_ln(hn, ng + (i * 2) * 128, nbeta + (i * 2) * 128);
    ea_mlp(i * 2);
    tconv(i * 2 + 1);
    // SAG pooling on pre-LN conv2 output hn; edge emb via linearity
    build_w2<<<64, 256, 0, stream>>>(up_w + (size_t)(i * 2 + 1) * 4096,
                                     up_b + (i * 2 + 1) * 64,
                                     re_w + (size_t)i * 64 * 128, W2, bvec, gsum_in);
    dim3 gsg(GG, 16);
    gsum_pre<<<gsg, 256, 0, stream>>>(ea, sg_start, sg_perm, gsum_in);
    if (i == 0) ea_mlp(i * 2 + 1);  // ea after last SAG is never consumed
    node_dots<<<NN / 4, 256, 0, stream>>>(hn, sag_wrel + i * 128, sag_wroot + i * 128,
                                          hrel, troot, gm, gs);
    sag_gather<<<(NN + 255) / 256, 256, 0, stream>>>(hrel, troot, sag_brel + i, row_start,
                                                     csr_src, batch, sc, gm);
    sag_exp<<<(NN + 255) / 256, 256, 0, stream>>>(sc, batch, gm, gs, scp);
    emb_e_kernel<<<GG, 128, 0, stream>>>(gsum_in, sg_start, W2, bvec, re_b + i * 128, embE);
    emb_block<<<GG, 128, 0, stream>>>(hn, scp, gs, gstart, embE, i == 0 ? embs0 : embs1);
    if (i == 0) graph_ln(hn, ng + (i * 2 + 1) * 128, nbeta + (i * 2 + 1) * 128);
  }
  final_combine<<<GG * 128 / 256, 256, 0, stream>>>(embs0, embs1, out);
}